// Round 15
// baseline (827.036 us; speedup 1.0000x reference)
//
#include <hip/hip_runtime.h>
#include <cstdint>
#include <cstddef>

typedef __attribute__((ext_vector_type(8))) short bf16x8;
typedef __attribute__((ext_vector_type(4))) float f32x4;
typedef unsigned short u16;
typedef unsigned int u32;

static constexpr float DN    = 0.42044820762685725f;   // 32^-0.25
static constexpr float DN2   = 0.17677669529663687f;   // 32^-0.5
static constexpr float RATIO = 0.09534625892455924f;   // 110^-0.5
static constexpr float KEPS  = 1e-4f;

__device__ __forceinline__ float b2f(u16 u) {
    union { float f; u32 i; } x; x.i = ((u32)u) << 16; return x.f;
}
__device__ __forceinline__ u16 f2b(float f) {
    union { float f; u32 i; } x; x.f = f;
    u32 r = (x.i + 0x7FFFu + ((x.i >> 16) & 1u)) >> 16;
    return (u16)r;
}
__device__ __forceinline__ float wred_sum(float v) {
#pragma unroll
    for (int o = 32; o > 0; o >>= 1) v += __shfl_xor(v, o, 64);
    return v;
}
__device__ __forceinline__ float gelu_f(float v) {
    return 0.5f * v * (1.f + erff(v * 0.7071067811865475f));
}
// async global->LDS, 16B per lane. LDS dest = wave-uniform base + lane*16.
__device__ __forceinline__ void gload16(const u16* g, u16* l) {
    __builtin_amdgcn_global_load_lds(
        (const __attribute__((address_space(1))) u32*)(const u32*)g,
        (__attribute__((address_space(3))) u32*)(u32*)l, 16, 0, 0);
}

// ---------------- weight transpose+cast: src f32 [K][N] -> dst bf16 [N][K] ----------------
__global__ __launch_bounds__(256) void trk(const float* __restrict__ src, u16* __restrict__ dst,
                                           int K, int N)
{
    const size_t bo = (size_t)blockIdx.z * K * N;
    src += bo; dst += bo;
    __shared__ float tl[32][33];
    const int t = threadIdx.x, tx = t & 31, ty = t >> 5;
    const int k0 = blockIdx.y * 32, n0 = blockIdx.x * 32;
#pragma unroll
    for (int p = 0; p < 4; ++p)
        tl[ty + p * 8][tx] = src[(size_t)(k0 + ty + p * 8) * N + n0 + tx];
    __syncthreads();
#pragma unroll
    for (int p = 0; p < 4; ++p)
        dst[(size_t)(n0 + ty + p * 8) * K + k0 + tx] = f2b(tl[tx][ty + p * 8]);
}

// ---------------- f32 transpose (no cast) ----------------
__global__ __launch_bounds__(256) void trkf(const float* __restrict__ src, float* __restrict__ dst,
                                            int K, int N)
{
    __shared__ float tl[32][33];
    const int t = threadIdx.x, tx = t & 31, ty = t >> 5;
    const int k0 = blockIdx.y * 32, n0 = blockIdx.x * 32;
#pragma unroll
    for (int p = 0; p < 4; ++p)
        tl[ty + p * 8][tx] = src[(size_t)(k0 + ty + p * 8) * N + n0 + tx];
    __syncthreads();
#pragma unroll
    for (int p = 0; p < 4; ++p)
        dst[(size_t)(n0 + ty + p * 8) * K + k0 + tx] = tl[tx][ty + p * 8];
}

// ---------------- x cast f32 -> bf16 ----------------
__global__ __launch_bounds__(256) void xcast(const float* __restrict__ x, u16* __restrict__ xb)
{
    const int i = blockIdx.x * 256 + threadIdx.x;
    const float4 v = ((const float4*)x)[i];
    uint2 r;
    r.x = (u32)f2b(v.x) | ((u32)f2b(v.y) << 16);
    r.y = (u32)f2b(v.z) | ((u32)f2b(v.w) << 16);
    ((uint2*)xb)[i] = r;
}

// ---------------- weight-stationary MFMA GEMM (row/chunk paths, as R14) ----------------
template<int CMODE, int NP, bool QKV, bool AHEAD, bool CHEAD, bool CHUNK, int DEPTH>
__global__ __launch_bounds__(512) void gemm3(
    const u16* __restrict__ A, const u16* __restrict__ Bt,
    const float* __restrict__ bias, u16* __restrict__ Cb, int ldc,
    u16* __restrict__ hres, const float* __restrict__ lng, const float* __restrict__ lnb,
    u16* __restrict__ yout, int K, int lda, int nrt)
{
    constexpr int KC    = (NP == 128) ? 256 : 128;
    constexpr int SLOTS = KC / 8;
    constexpr int SSH   = (SLOTS == 32) ? 5 : 4;
    constexpr int BB    = NP * KC * 2;
    constexpr int ABYT  = 64 * KC * 2;
    constexpr int NCB   = NP / 128;
    constexpr int CTS   = (NP == 128) ? 136 : 264;
    constexpr int EPI   = (CMODE <= 1) ? (64 * CTS * 2) : (64 * 264 * 2 + 4608);
    constexpr int KCC   = 64;
    constexpr int BBC   = 256 * KCC * 2;
    constexpr int ABYTC = 64 * KCC * 2;
    constexpr int BUF   = BBC + ABYTC;
    constexpr int LDSZ  = CHUNK ? (DEPTH * BUF) : (BB + 2 * ABYT + EPI);
    __shared__ __align__(16) char smem[LDSZ];

    const u16* Btl = Bt;
    u16* Cbl = Cb;
    if (QKV) { Btl += (size_t)blockIdx.z * 393216; Cbl += (size_t)blockIdx.z * 4194304; }
    const int t = threadIdx.x, w = t >> 6, lr = (t & 63) & 15, lg = (t & 63) >> 4;
    const int p = blockIdx.x;

    char* epi = CHUNK ? smem : (smem + BB + 2 * ABYT);

    f32x4 acc[4][NCB];
    auto ZERO = [&]() {
#pragma unroll
        for (int i = 0; i < 4; ++i)
#pragma unroll
            for (int j = 0; j < NCB; ++j) acc[i][j] = f32x4{0.f, 0.f, 0.f, 0.f};
    };

    auto EPILOGUE = [&](int row0) {
        if constexpr (CMODE <= 1) {
            u16* ctile = (u16*)epi;
            float bv[NCB];
#pragma unroll
            for (int cb = 0; cb < NCB; ++cb) {
                const int col = p * NP + w * (NP / 8) + cb * 16 + lr;
                bv[cb] = bias ? bias[col] : 0.f;
            }
#pragma unroll
            for (int rbk = 0; rbk < 4; ++rbk)
#pragma unroll
                for (int cb = 0; cb < NCB; ++cb)
#pragma unroll
                    for (int rr = 0; rr < 4; ++rr) {
                        const int rl = rbk * 16 + 4 * lg + rr;
                        float v = acc[rbk][cb][rr] + bv[cb];
                        if (CMODE == 1) v = gelu_f(v);
                        ctile[rl * CTS + w * (NP / 8) + cb * 16 + lr] = f2b(v);
                    }
            __syncthreads();
            if constexpr (CHEAD && NP == 128) {
                const int bq = row0 >> 12, n0 = row0 & 4095;
#pragma unroll
                for (int i = 0; i < 2; ++i) {
                    const int u = i * 512 + t;
                    const int hh = u >> 8, rem = u & 255;
                    const int row = rem >> 2, dblk = rem & 3;
                    *(uint4*)(Cbl + ((size_t)(bq * 8 + p * 4 + hh) * 4096 + n0 + row) * 32 + dblk * 8)
                        = *(const uint4*)&ctile[row * CTS + hh * 32 + dblk * 8];
                }
            } else if constexpr (CHEAD && NP == 256) {
                const int bq = row0 >> 12, n0 = row0 & 4095;
#pragma unroll
                for (int i = 0; i < 4; ++i) {
                    const int u = i * 512 + t;
                    const int row = u >> 5, seg = u & 31;
                    const int hh = seg >> 2, dblk = seg & 3;
                    *(uint4*)(Cbl + ((size_t)(bq * 8 + hh) * 4096 + n0 + row) * 32 + dblk * 8)
                        = *(const uint4*)&ctile[row * 264 + seg * 8];
                }
            } else {
                constexpr int NIT = (NP == 128) ? 2 : 4;
                constexpr int SEGM = NP / 8 - 1;
                constexpr int RSH = (NP == 128) ? 4 : 5;
#pragma unroll
                for (int i = 0; i < NIT; ++i) {
                    const int u = i * 512 + t;
                    const int row = u >> RSH, seg = u & SEGM;
                    *(uint4*)(Cbl + (size_t)(row0 + row) * ldc + p * NP + seg * 8)
                        = *(const uint4*)&ctile[row * CTS + seg * 8];
                }
            }
        } else {
            u16*   ctile = (u16*)epi;
            float* rsum  = (float*)(epi + 33792);
            float* rsum2 = rsum + 512;
            float* rmu   = rsum2 + 512;
            float* rrs   = rmu + 64;
            int cidx[NCB]; float bv[NCB];
#pragma unroll
            for (int cb = 0; cb < NCB; ++cb) {
                cidx[cb] = w * 32 + cb * 16 + lr;
                bv[cb] = bias ? bias[cidx[cb]] : 0.f;
            }
            if constexpr (CMODE == 2 || CMODE == 4) {
#pragma unroll
                for (int i = 0; i < 4; ++i) {
                    const int u = i * 512 + t;
                    const int row = u >> 5, seg = u & 31;
                    *(uint4*)&ctile[row * 264 + seg * 8]
                        = *(const uint4*)(hres + (size_t)(row0 + row) * 256 + seg * 8);
                }
                __syncthreads();
            }
#pragma unroll
            for (int rbk = 0; rbk < 4; ++rbk)
#pragma unroll
                for (int cb = 0; cb < NCB; ++cb)
#pragma unroll
                    for (int rr = 0; rr < 4; ++rr) {
                        const int rl = rbk * 16 + 4 * lg + rr;
                        float v = acc[rbk][cb][rr] + bv[cb];
                        if constexpr (CMODE == 2 || CMODE == 4)
                            v += b2f(ctile[rl * 264 + cidx[cb]]);
                        acc[rbk][cb][rr] = v;
                    }
            __syncthreads();
            if constexpr (CMODE != 4) {
#pragma unroll
                for (int rbk = 0; rbk < 4; ++rbk)
#pragma unroll
                    for (int rr = 0; rr < 4; ++rr) {
                        float s1 = acc[rbk][0][rr] + acc[rbk][NCB - 1][rr];
                        float s2 = fmaf(acc[rbk][0][rr], acc[rbk][0][rr],
                                        acc[rbk][NCB - 1][rr] * acc[rbk][NCB - 1][rr]);
#pragma unroll
                        for (int off = 1; off < 16; off <<= 1) {
                            s1 += __shfl_xor(s1, off, 64);
                            s2 += __shfl_xor(s2, off, 64);
                        }
                        if (lr == 0) {
                            const int rl = rbk * 16 + 4 * lg + rr;
                            rsum[rl * 8 + w] = s1; rsum2[rl * 8 + w] = s2;
                        }
                    }
                __syncthreads();
                if (t < 64) {
                    float s1 = 0.f, s2 = 0.f;
#pragma unroll
                    for (int j = 0; j < 8; ++j) { s1 += rsum[t * 8 + j]; s2 += rsum2[t * 8 + j]; }
                    const float mu = s1 * (1.f / 256.f);
                    const float var = s2 * (1.f / 256.f) - mu * mu;
                    rmu[t] = mu; rrs[t] = rsqrtf(var + 1e-5f);
                }
                __syncthreads();
            }
#pragma unroll
            for (int rbk = 0; rbk < 4; ++rbk)
#pragma unroll
                for (int cb = 0; cb < NCB; ++cb)
#pragma unroll
                    for (int rr = 0; rr < 4; ++rr) {
                        const int rl = rbk * 16 + 4 * lg + rr;
                        ctile[rl * 264 + cidx[cb]] = f2b(acc[rbk][cb][rr]);
                    }
            __syncthreads();
#pragma unroll
            for (int i = 0; i < 4; ++i) {
                const int u = i * 512 + t;
                const int row = u >> 5, seg = u & 31;
                *(uint4*)(hres + (size_t)(row0 + row) * 256 + seg * 8)
                    = *(const uint4*)&ctile[row * 264 + seg * 8];
            }
            if constexpr (CMODE != 4) {
                __syncthreads();
                float gv[NCB], bb2[NCB];
#pragma unroll
                for (int cb = 0; cb < NCB; ++cb) { gv[cb] = lng[cidx[cb]]; bb2[cb] = lnb[cidx[cb]]; }
#pragma unroll
                for (int rbk = 0; rbk < 4; ++rbk)
#pragma unroll
                    for (int cb = 0; cb < NCB; ++cb)
#pragma unroll
                        for (int rr = 0; rr < 4; ++rr) {
                            const int rl = rbk * 16 + 4 * lg + rr;
                            const float yv = (acc[rbk][cb][rr] - rmu[rl]) * rrs[rl] * gv[cb] + bb2[cb];
                            ctile[rl * 264 + cidx[cb]] = f2b(yv);
                        }
                __syncthreads();
#pragma unroll
                for (int i = 0; i < 4; ++i) {
                    const int u = i * 512 + t;
                    const int row = u >> 5, seg = u & 31;
                    *(uint4*)(yout + (size_t)(row0 + row) * 256 + seg * 8)
                        = *(const uint4*)&ctile[row * 264 + seg * 8];
                }
            }
        }
    };

    if constexpr (!CHUNK) {
        u16* Bs  = (u16*)smem;
        u16* Asm = (u16*)(smem + BB);
        auto STAGE_B = [&](int c) {
#pragma unroll
            for (int i = 0; i < BB / 16 / 512; ++i) {
                const int u = i * 512 + t;
                const int col = u >> SSH, slot = u & (SLOTS - 1);
                const int gs = slot ^ (col & 7);
                gload16(Btl + (size_t)(p * NP + col) * K + c * KC + gs * 8, Bs + u * 8);
            }
        };
        auto STAGE_A = [&](int c, int row0, int buf) {
            u16* dst = Asm + buf * (ABYT / 2);
#pragma unroll
            for (int i = 0; i < ABYT / 16 / 512; ++i) {
                const int u = i * 512 + t;
                const int row = u >> SSH, slot = u & (SLOTS - 1);
                const int gs = slot ^ (row & 7);
                const u16* src;
                if (AHEAD) {
                    const int kg = c * KC + gs * 8;
                    src = A + ((size_t)((row0 >> 12) * 8 + (kg >> 5)) * 4096 + (row0 & 4095) + row) * 32 + (kg & 31);
                } else {
                    src = A + (size_t)(row0 + row) * lda + c * KC + gs * 8;
                }
                gload16(src, dst + u * 8);
            }
        };
        auto KLOOP = [&](const u16* AcC) {
#pragma unroll
            for (int ks = 0; ks < KC / 32; ++ks) {
                bf16x8 af[4], bfv[NCB];
#pragma unroll
                for (int rbk = 0; rbk < 4; ++rbk) {
                    const int row = rbk * 16 + lr;
                    af[rbk] = *(const bf16x8*)&AcC[row * KC + (((ks * 4 + lg) ^ (row & 7)) << 3)];
                }
#pragma unroll
                for (int cb = 0; cb < NCB; ++cb) {
                    const int col = w * (NP / 8) + cb * 16 + lr;
                    bfv[cb] = *(const bf16x8*)&Bs[col * KC + (((ks * 4 + lg) ^ (col & 7)) << 3)];
                }
#pragma unroll
                for (int rbk = 0; rbk < 4; ++rbk)
#pragma unroll
                    for (int cb = 0; cb < NCB; ++cb)
                        acc[rbk][cb] = __builtin_amdgcn_mfma_f32_16x16x32_bf16(af[rbk], bfv[cb], acc[rbk][cb], 0, 0, 0);
            }
        };
        int ab = 0;
        STAGE_B(0);
        STAGE_A(0, blockIdx.y * nrt * 64, 0);
        asm volatile("s_waitcnt vmcnt(0)" ::: "memory");
        __syncthreads();
        for (int rt = 0; rt < nrt; ++rt) {
            const int row0 = (blockIdx.y * nrt + rt) * 64;
            if (rt + 1 < nrt) STAGE_A(0, row0 + 64, ab ^ 1);
            ZERO();
            KLOOP(Asm + ab * (ABYT / 2));
            EPILOGUE(row0);
            asm volatile("s_waitcnt vmcnt(0)" ::: "memory");
            __syncthreads();
            ab ^= 1;
        }
    } else {
        const int NC = K / KCC;
        const int row0 = blockIdx.y * 64;
        auto STAGE_CH = [&](int c, int b) {
            u16* bsB = (u16*)(smem + b * BUF);
            u16* bsA = (u16*)(smem + b * BUF + BBC);
#pragma unroll
            for (int i = 0; i < BBC / 16 / 512; ++i) {
                const int u = i * 512 + t;
                const int col = u >> 3, slot = u & 7;
                const int gs = slot ^ (col & 7);
                gload16(Btl + (size_t)(p * NP + col) * K + c * KCC + gs * 8, bsB + u * 8);
            }
            {
                const int u = t;
                const int row = u >> 3, slot = u & 7;
                const int gs = slot ^ (row & 7);
                const u16* src;
                if (AHEAD) {
                    const int kg = c * KCC + gs * 8;
                    src = A + ((size_t)((row0 >> 12) * 8 + (kg >> 5)) * 4096 + (row0 & 4095) + row) * 32 + (kg & 31);
                } else {
                    src = A + (size_t)(row0 + row) * lda + c * KCC + gs * 8;
                }
                gload16(src, bsA + u * 8);
            }
        };
        auto KLOOP_C = [&](const u16* BsC, const u16* AcC) {
#pragma unroll
            for (int ks = 0; ks < 2; ++ks) {
                bf16x8 af[4], bfv[NCB];
#pragma unroll
                for (int rbk = 0; rbk < 4; ++rbk) {
                    const int row = rbk * 16 + lr;
                    af[rbk] = *(const bf16x8*)&AcC[row * KCC + (((ks * 4 + lg) ^ (row & 7)) << 3)];
                }
#pragma unroll
                for (int cb = 0; cb < NCB; ++cb) {
                    const int col = w * 32 + cb * 16 + lr;
                    bfv[cb] = *(const bf16x8*)&BsC[col * KCC + (((ks * 4 + lg) ^ (col & 7)) << 3)];
                }
#pragma unroll
                for (int rbk = 0; rbk < 4; ++rbk)
#pragma unroll
                    for (int cb = 0; cb < NCB; ++cb)
                        acc[rbk][cb] = __builtin_amdgcn_mfma_f32_16x16x32_bf16(af[rbk], bfv[cb], acc[rbk][cb], 0, 0, 0);
            }
        };

        ZERO();
#pragma unroll
        for (int d = 0; d < DEPTH; ++d)
            if (d < NC) STAGE_CH(d, d);
        for (int c = 0; c < NC; ++c) {
            const int rem = NC - 1 - c;
            if constexpr (DEPTH == 3) {
                if (rem >= 2)      asm volatile("s_waitcnt vmcnt(10)" ::: "memory");
                else if (rem == 1) asm volatile("s_waitcnt vmcnt(5)"  ::: "memory");
                else               asm volatile("s_waitcnt vmcnt(0)"  ::: "memory");
            } else {
                if (rem >= 1)      asm volatile("s_waitcnt vmcnt(5)"  ::: "memory");
                else               asm volatile("s_waitcnt vmcnt(0)"  ::: "memory");
            }
            __builtin_amdgcn_s_barrier();
            __builtin_amdgcn_sched_barrier(0);
            const int cb_ = c % DEPTH;
            KLOOP_C((const u16*)(smem + cb_ * BUF),
                    (const u16*)(smem + cb_ * BUF + BBC));
            __builtin_amdgcn_sched_barrier(0);
            if (c + DEPTH < NC) {
                __builtin_amdgcn_s_barrier();
                __builtin_amdgcn_sched_barrier(0);
                STAGE_CH(c + DEPTH, cb_);
            }
        }
        __builtin_amdgcn_s_barrier();
        __builtin_amdgcn_sched_barrier(0);
        EPILOGUE(row0);
    }
}

// ---------------- fused FF1+FF2: mid never touches HBM ----------------
// grid 256 (64-row blocks), 512 thr. y panel + mid panel in LDS; weights stream KC=64
// ping-pong with counted vmcnt(4). CMODE2: 2 = h+=..,+LN->y ; 4 = h+=.. only.
template<int CMODE2>
__global__ __launch_bounds__(512) void ffuse(
    const u16* __restrict__ yg, const u16* __restrict__ w1T, const float* __restrict__ b1,
    const u16* __restrict__ w2T, const float* __restrict__ b2,
    u16* __restrict__ hres, const float* __restrict__ lng, const float* __restrict__ lnb,
    u16* __restrict__ yout)
{
    __shared__ __align__(16) char smem[131072];
    u16* yS   = (u16*)smem;                 // [64][256] swizzled per-64K-chunk
    u16* midS = (u16*)(smem + 32768);       // [64][256] same layout
    u16* wb   = (u16*)(smem + 65536);       // 2 x 32KB weight chunk buffers
    char* epi = smem + 65536;               // epilogue overlays wbuf (38400 <= 65536)

    const int t = threadIdx.x, w = t >> 6, lr = (t & 63) & 15, lg = (t & 63) >> 4;
    const int row0 = blockIdx.x * 64;

    // stage yS (4 loads/thread)
#pragma unroll
    for (int i = 0; i < 4; ++i) {
        const int u = i * 512 + t;
        const int row = u >> 5, s32 = u & 31;
        const int kc = s32 >> 3, sl = s32 & 7;
        const int gs = sl ^ (row & 7);
        gload16(yg + (size_t)(row0 + row) * 256 + kc * 64 + gs * 8, yS + u * 8);
    }

    auto STAGE_J = [&](int j, int b) {      // 4 loads/thread
        const int mp = j >> 3, ph = (j >> 2) & 1, kc = j & 3;
        u16* dst = wb + b * 16384;
#pragma unroll
        for (int i = 0; i < 4; ++i) {
            const int u = i * 512 + t;
            const int col = u >> 3, sl = u & 7;
            const int gs = sl ^ (col & 7);
            const u16* src = (ph == 0)
                ? (w1T + (size_t)(mp * 256 + col) * 256 + kc * 64 + gs * 8)
                : (w2T + (size_t)col * 1024 + mp * 256 + kc * 64 + gs * 8);
            gload16(src, dst + u * 8);
        }
    };

    f32x4 acc1[4][2], acc2[4][2];
#pragma unroll
    for (int i = 0; i < 4; ++i)
#pragma unroll
        for (int j = 0; j < 2; ++j) acc2[i][j] = f32x4{0.f, 0.f, 0.f, 0.f};

    STAGE_J(0, 0);
    STAGE_J(1, 1);

#pragma unroll
    for (int j = 0; j < 32; ++j) {
        if (j < 31) asm volatile("s_waitcnt vmcnt(4)" ::: "memory");
        else        asm volatile("s_waitcnt vmcnt(0)" ::: "memory");
        __builtin_amdgcn_s_barrier();
        __builtin_amdgcn_sched_barrier(0);
        const int mp = j >> 3, ph = (j >> 2) & 1, kc = j & 3;
        const u16* wc = wb + (j & 1) * 16384;
        if (ph == 0) {
            if (kc == 0) {
#pragma unroll
                for (int i = 0; i < 4; ++i)
#pragma unroll
                    for (int jj = 0; jj < 2; ++jj) acc1[i][jj] = f32x4{0.f, 0.f, 0.f, 0.f};
            }
#pragma unroll
            for (int ks = 0; ks < 2; ++ks) {
                bf16x8 af[4], bfv[2];
#pragma unroll
                for (int rbk = 0; rbk < 4; ++rbk) {
                    const int row = rbk * 16 + lr;
                    af[rbk] = *(const bf16x8*)&yS[row * 256 + kc * 64 + (((ks * 4 + lg) ^ (row & 7)) << 3)];
                }
#pragma unroll
                for (int cb = 0; cb < 2; ++cb) {
                    const int col = w * 32 + cb * 16 + lr;
                    bfv[cb] = *(const bf16x8*)&wc[col * 64 + (((ks * 4 + lg) ^ (col & 7)) << 3)];
                }
#pragma unroll
                for (int rbk = 0; rbk < 4; ++rbk)
#pragma unroll
                    for (int cb = 0; cb < 2; ++cb)
                        acc1[rbk][cb] = __builtin_amdgcn_mfma_f32_16x16x32_bf16(af[rbk], bfv[cb], acc1[rbk][cb], 0, 0, 0);
            }
        } else {
#pragma unroll
            for (int ks = 0; ks < 2; ++ks) {
                bf16x8 af[4], bfv[2];
#pragma unroll
                for (int rbk = 0; rbk < 4; ++rbk) {
                    const int row = rbk * 16 + lr;
                    af[rbk] = *(const bf16x8*)&midS[row * 256 + kc * 64 + (((ks * 4 + lg) ^ (row & 7)) << 3)];
                }
#pragma unroll
                for (int cb = 0; cb < 2; ++cb) {
                    const int col = w * 32 + cb * 16 + lr;
                    bfv[cb] = *(const bf16x8*)&wc[col * 64 + (((ks * 4 + lg) ^ (col & 7)) << 3)];
                }
#pragma unroll
                for (int rbk = 0; rbk < 4; ++rbk)
#pragma unroll
                    for (int cb = 0; cb < 2; ++cb)
                        acc2[rbk][cb] = __builtin_amdgcn_mfma_f32_16x16x32_bf16(af[rbk], bfv[cb], acc2[rbk][cb], 0, 0, 0);
            }
        }
        __builtin_amdgcn_sched_barrier(0);
        if (ph == 0 && kc == 3) {
            // gelu + write mid panel into midS (swizzled, bf16)
#pragma unroll
            for (int rbk = 0; rbk < 4; ++rbk)
#pragma unroll
                for (int cb = 0; cb < 2; ++cb) {
                    const int col = w * 32 + cb * 16 + lr;
                    const float bv = b1[mp * 256 + col];
#pragma unroll
                    for (int rr = 0; rr < 4; ++rr) {
                        const int row = rbk * 16 + 4 * lg + rr;
                        const float v = gelu_f(acc1[rbk][cb][rr] + bv);
                        midS[row * 256 + (col & ~63) + ((((col >> 3) & 7) ^ (row & 7)) << 3) + (col & 7)] = f2b(v);
                    }
                }
            asm volatile("s_waitcnt lgkmcnt(0)" ::: "memory");
            __builtin_amdgcn_sched_barrier(0);
        }
        if (j + 2 < 32) {
            __builtin_amdgcn_s_barrier();
            __builtin_amdgcn_sched_barrier(0);
            STAGE_J(j + 2, j & 1);
        }
    }
    __builtin_amdgcn_s_barrier();
    __builtin_amdgcn_sched_barrier(0);

    // ---- epilogue: h += acc2 + b2 (+ LN -> yout) ----
    u16*   ctile = (u16*)epi;                 // [64][264]
    float* rsum  = (float*)(epi + 33792);
    float* rsum2 = rsum + 512;
    float* rmu   = rsum2 + 512;
    float* rrs   = rmu + 64;
    int cidx[2]; float bv[2];
#pragma unroll
    for (int cb = 0; cb < 2; ++cb) {
        cidx[cb] = w * 32 + cb * 16 + lr;
        bv[cb] = b2[cidx[cb]];
    }
#pragma unroll
    for (int i = 0; i < 4; ++i) {
        const int u = i * 512 + t;
        const int row = u >> 5, seg = u & 31;
        *(uint4*)&ctile[row * 264 + seg * 8]
            = *(const uint4*)(hres + (size_t)(row0 + row) * 256 + seg * 8);
    }
    __syncthreads();
#pragma unroll
    for (int rbk = 0; rbk < 4; ++rbk)
#pragma unroll
        for (int cb = 0; cb < 2; ++cb)
#pragma unroll
            for (int rr = 0; rr < 4; ++rr) {
                const int rl = rbk * 16 + 4 * lg + rr;
                acc2[rbk][cb][rr] += bv[cb] + b2f(ctile[rl * 264 + cidx[cb]]);
            }
    __syncthreads();
    if constexpr (CMODE2 != 4) {
#pragma unroll
        for (int rbk = 0; rbk < 4; ++rbk)
#pragma unroll
            for (int rr = 0; rr < 4; ++rr) {
                float s1 = acc2[rbk][0][rr] + acc2[rbk][1][rr];
                float s2 = fmaf(acc2[rbk][0][rr], acc2[rbk][0][rr],
                                acc2[rbk][1][rr] * acc2[rbk][1][rr]);
#pragma unroll
                for (int off = 1; off < 16; off <<= 1) {
                    s1 += __shfl_xor(s1, off, 64);
                    s2 += __shfl_xor(s2, off, 64);
                }
                if (lr == 0) {
                    const int rl = rbk * 16 + 4 * lg + rr;
                    rsum[rl * 8 + w] = s1; rsum2[rl * 8 + w] = s2;
                }
            }
        __syncthreads();
        if (t < 64) {
            float s1 = 0.f, s2 = 0.f;
#pragma unroll
            for (int jj = 0; jj < 8; ++jj) { s1 += rsum[t * 8 + jj]; s2 += rsum2[t * 8 + jj]; }
            const float mu = s1 * (1.f / 256.f);
            const float var = s2 * (1.f / 256.f) - mu * mu;
            rmu[t] = mu; rrs[t] = rsqrtf(var + 1e-5f);
        }
        __syncthreads();
    }
#pragma unroll
    for (int rbk = 0; rbk < 4; ++rbk)
#pragma unroll
        for (int cb = 0; cb < 2; ++cb)
#pragma unroll
            for (int rr = 0; rr < 4; ++rr) {
                const int rl = rbk * 16 + 4 * lg + rr;
                ctile[rl * 264 + cidx[cb]] = f2b(acc2[rbk][cb][rr]);
            }
    __syncthreads();
#pragma unroll
    for (int i = 0; i < 4; ++i) {
        const int u = i * 512 + t;
        const int row = u >> 5, seg = u & 31;
        *(uint4*)(hres + (size_t)(row0 + row) * 256 + seg * 8)
            = *(const uint4*)&ctile[row * 264 + seg * 8];
    }
    if constexpr (CMODE2 != 4) {
        __syncthreads();
        float gv[2], bb2[2];
#pragma unroll
        for (int cb = 0; cb < 2; ++cb) { gv[cb] = lng[cidx[cb]]; bb2[cb] = lnb[cidx[cb]]; }
#pragma unroll
        for (int rbk = 0; rbk < 4; ++rbk)
#pragma unroll
            for (int cb = 0; cb < 2; ++cb)
#pragma unroll
                for (int rr = 0; rr < 4; ++rr) {
                    const int rl = rbk * 16 + 4 * lg + rr;
                    const float yv = (acc2[rbk][cb][rr] - rmu[rl]) * rrs[rl] * gv[cb] + bb2[cb];
                    ctile[rl * 264 + cidx[cb]] = f2b(yv);
                }
        __syncthreads();
#pragma unroll
        for (int i = 0; i < 4; ++i) {
            const int u = i * 512 + t;
            const int row = u >> 5, seg = u & 31;
            *(uint4*)(yout + (size_t)(row0 + row) * 256 + seg * 8)
                = *(const uint4*)&ctile[row * 264 + seg * 8];
        }
    }
}

// ---------------- Performer K-side ----------------
__global__ __launch_bounds__(256) void kctx2(
    const u16* __restrict__ kg, const u16* __restrict__ vg,
    const float* __restrict__ proj, float* __restrict__ ctxp, float* __restrict__ Mcp,
    float* __restrict__ vsump)
{
    __shared__ __align__(16) u16 projS[112 * 32];
    __shared__ __align__(16) u16 kS[128 * 32];
    __shared__ __align__(16) u16 vTS[48 * 128];
    __shared__ __align__(16) u16 eTS[112 * 128];
    __shared__ float diagS[128];
    __shared__ float redS[4];
    const int t = threadIdx.x, w = t >> 6, lane = t & 63, lr = lane & 15, lg = lane >> 4;
    const int bh = blockIdx.x >> 3, chunk = blockIdx.x & 7;

    for (int idx = t; idx < 112 * 32; idx += 256) {
        const int m = idx >> 5, d = idx & 31;
        projS[idx] = (m < 110) ? f2b(proj[m * 32 + d] * DN) : (u16)0;
    }
    for (int idx = t; idx < 16 * 128; idx += 256) {
        const int rr = idx >> 7;
        vTS[(32 + rr) * 128 + (idx & 127)] = (rr == 0) ? f2b(1.0f) : (u16)0;
    }
    for (int idx = t; idx < 16 * 128; idx += 256)
        eTS[112 * 128 + idx] = 0;

    f32x4 E[2][3];
#pragma unroll
    for (int i = 0; i < 2; ++i)
#pragma unroll
        for (int j = 0; j < 3; ++j) E[i][j] = f32x4{0.f, 0.f, 0.f, 0.f};
    float Mrun = -INFINITY;
    float vsAcc = 0.f;

    for (int r = 0; r < 4; ++r) {
        const size_t eb = ((size_t)bh * 4096 + chunk * 512 + r * 128) * 32;
#pragma unroll
        for (int i = 0; i < 2; ++i) {
            const int u = i * 256 + t;
            ((uint4*)kS)[u] = ((const uint4*)(kg + eb))[u];
        }
#pragma unroll
        for (int i = 0; i < 2; ++i) {
            const int u = i * 256 + t;
            const int tok = u >> 2, dblk = u & 3;
            union { uint4 v; u16 s[8]; } uu;
            uu.v = ((const uint4*)(vg + eb))[u];
#pragma unroll
            for (int j = 0; j < 8; ++j) {
                const int d = dblk * 8 + j;
                vTS[d * 128 + ((((tok >> 3) ^ (d & 15))) << 3) + (tok & 7)] = uu.s[j];
            }
        }
        __syncthreads();
        {
            const int d = t >> 3, seg = t & 7;
            union { uint4 v; u16 s[8]; } ua, ub;
            ua.v = *(const uint4*)&vTS[d * 128 + seg * 16];
            ub.v = *(const uint4*)&vTS[d * 128 + seg * 16 + 8];
            float s = 0.f;
#pragma unroll
            for (int j = 0; j < 8; ++j) s += b2f(ua.s[j]) + b2f(ub.s[j]);
            vsAcc += s;
        }
        if (t < 128) {
            float s = 0.f;
#pragma unroll
            for (int dq = 0; dq < 4; ++dq) {
                union { uint4 v; u16 ss[8]; } uu;
                uu.v = ((const uint4*)kS)[t * 4 + dq];
#pragma unroll
                for (int j = 0; j < 8; ++j) { const float f = b2f(uu.ss[j]); s = fmaf(f, f, s); }
            }
            diagS[t] = 0.5f * DN2 * s;
        }
        __syncthreads();
        f32x4 dd[7][2];
#pragma unroll
        for (int mb = 0; mb < 7; ++mb)
#pragma unroll
            for (int tb = 0; tb < 2; ++tb) dd[mb][tb] = f32x4{0.f, 0.f, 0.f, 0.f};
        bf16x8 kf[2];
#pragma unroll
        for (int tb = 0; tb < 2; ++tb)
            kf[tb] = *(const bf16x8*)&kS[(w * 32 + tb * 16 + lr) * 32 + lg * 8];
#pragma unroll
        for (int mb = 0; mb < 7; ++mb) {
            const bf16x8 pf = *(const bf16x8*)&projS[(mb * 16 + lr) * 32 + lg * 8];
#pragma unroll
            for (int tb = 0; tb < 2; ++tb)
                dd[mb][tb] = __builtin_amdgcn_mfma_f32_16x16x32_bf16(pf, kf[tb], dd[mb][tb], 0, 0, 0);
        }
        float mx = -INFINITY;
#pragma unroll
        for (int mb = 0; mb < 7; ++mb)
#pragma unroll
            for (int tb = 0; tb < 2; ++tb)
#pragma unroll
                for (int rr = 0; rr < 4; ++rr) {
                    if (mb == 6 && (4 * lg + rr) >= 14) continue;
                    mx = fmaxf(mx, dd[mb][tb][rr]);
                }
#pragma unroll
        for (int off = 1; off < 64; off <<= 1) mx = fmaxf(mx, __shfl_xor(mx, off, 64));
        if (lane == 0) redS[w] = mx;
        __syncthreads();
        float Mnew = fmaxf(fmaxf(redS[0], redS[1]), fmaxf(redS[2], redS[3]));
        Mnew = fmaxf(Mrun, Mnew);
        const float scl = __expf(Mrun - Mnew);
#pragma unroll
        for (int i = 0; i < 2; ++i)
#pragma unroll
            for (int j = 0; j < 3; ++j)
#pragma unroll
                for (int rr = 0; rr < 4; ++rr) E[i][j][rr] *= scl;
        Mrun = Mnew;
        const float dg0 = diagS[w * 32 + lr], dg1 = diagS[w * 32 + 16 + lr];
#pragma unroll
        for (int mb = 0; mb < 7; ++mb)
#pragma unroll
            for (int tb = 0; tb < 2; ++tb)
#pragma unroll
                for (int rr = 0; rr < 4; ++rr) {
                    const int tok = w * 32 + tb * 16 + lr;
                    const int m = mb * 16 + 4 * lg + rr;
                    const float e = __expf(dd[mb][tb][rr] - (tb ? dg1 : dg0) - Mnew);
                    eTS[m * 128 + ((((tok >> 3) ^ (m & 15))) << 3) + (tok & 7)] = f2b(e);
                }
        __syncthreads();
#pragma unroll
        for (int ks = 0; ks < 4; ++ks) {
            bf16x8 aF[2], bF[3];
#pragma unroll
            for (int mb2 = 0; mb2 < 2; ++mb2) {
                const int m = w * 32 + mb2 * 16 + lr;
                aF[mb2] = *(const bf16x8*)&eTS[m * 128 + (((ks * 4 + lg) ^ lr) << 3)];
            }
#pragma unroll
            for (int nb = 0; nb < 3; ++nb) {
                const int d = nb * 16 + lr;
                bF[nb] = *(const bf16x8*)&vTS[d * 128 + (((ks * 4 + lg) ^ lr) << 3)];
            }
#pragma unroll
            for (int mb2 = 0; mb2 < 2; ++mb2)
#pragma unroll
                for (int nb = 0; nb < 3; ++nb)
                    E[mb2][nb] = __builtin_amdgcn_mfma_f32_16x16x32_bf16(aF[mb2], bF[nb], E[mb2][nb], 0, 0, 0);
        }
        __syncthreads();
    }
    const size_t ob = (size_t)blockIdx.x * 112 * 33;
#pragma unroll
    for (int mb2 = 0; mb2 < 2; ++mb2)
#pragma unroll
        for (int nb = 0; nb < 3; ++nb)
#pragma unroll
            for (int rr = 0; rr < 4; ++rr) {
                const int m = w * 32 + mb2 * 16 + 4 * lg + rr;
                if (m < 112) {
                    if (nb < 2) ctxp[ob + m * 33 + nb * 16 + lr] = E[mb2][nb][rr];
                    else if (lr == 0) ctxp[ob + m * 33 + 32] = E[mb2][nb][rr];
                }
            }
    if (t == 0) Mcp[blockIdx.x] = Mrun;
    float vs = vsAcc;
#pragma unroll
    for (int o = 4; o > 0; o >>= 1) vs += __shfl_xor(vs, o, 64);
    if ((t & 7) == 0) vsump[blockIdx.x * 32 + (t >> 3)] = vs;
}

// ---------------- reduce chunk partials -> ctxT + ksum ----------------
__global__ __launch_bounds__(256) void kred2(
    const float* __restrict__ ctxp, const float* __restrict__ Mcp,
    const float* __restrict__ vsump,
    u16* __restrict__ ctxTg, float* __restrict__ ksumg)
{
    __shared__ float vsumS[32];
    __shared__ float wS[8];
    const int t = threadIdx.x, bh = blockIdx.x;
    float M = -INFINITY;
#pragma unroll
    for (int c = 0; c < 8; ++c) M = fmaxf(M, Mcp[bh * 8 + c]);
    if (t < 8) wS[t] = __expf(Mcp[bh * 8 + t] - M);
    if (t < 32) {
        float s = 0.f;
#pragma unroll
        for (int c = 0; c < 8; ++c) s += vsump[(bh * 8 + c) * 32 + t];
        vsumS[t] = s;
    }
    __syncthreads();
    for (int idx = t; idx < 4096; idx += 256) {
        const int d = idx >> 7, m = idx & 127;
        float val = 0.f;
        if (m < 110) {
            float s = 0.f;
#pragma unroll
            for (int c = 0; c < 8; ++c)
                s += wS[c] * ctxp[((size_t)(bh * 8 + c) * 112 + m) * 33 + d];
            val = RATIO * (s + KEPS * vsumS[d]);
        }
        ctxTg[(size_t)bh * 4096 + idx] = f2b(val);
    }
    if (t < 128) {
        float val = 0.f;
        if (t < 110) {
            float s = 0.f;
#pragma unroll
            for (int c = 0; c < 8; ++c)
                s += wS[c] * ctxp[((size_t)(bh * 8 + c) * 112 + t) * 33 + 32];
            val = RATIO * (s + KEPS * 4096.0f);
        }
        ksumg[bh * 128 + t] = val;
    }
}

// ---------------- Performer Q-side ----------------
__global__ __launch_bounds__(256) void qattn2(
    const u16* __restrict__ qg, const float* __restrict__ proj,
    const u16* __restrict__ ctxTg, const float* __restrict__ ksumg, u16* __restrict__ ag)
{
    __shared__ __align__(16) u16 projS[112 * 32];
    __shared__ __align__(16) u16 qS[128 * 32];
    __shared__ __align__(16) u16 ctxTS[32 * 128];
    __shared__ __align__(16) u16 pS[128 * 128];
    __shared__ float ksumS[128], diagS[128], dinvS[128];
    const int t = threadIdx.x, w = t >> 6, lr = (t & 63) & 15, lg = (t & 63) >> 4;
    const int bh = blockIdx.x >> 5, chunk = blockIdx.x & 31;

    for (int idx = t; idx < 112 * 32; idx += 256) {
        const int m = idx >> 5, d = idx & 31;
        projS[idx] = (m < 110) ? f2b(proj[m * 32 + d] * DN) : (u16)0;
    }
#pragma unroll
    for (int i = 0; i < 2; ++i) {
        const int u = i * 256 + t;
        const int d = u >> 4, s = u & 15;
        *(uint4*)&ctxTS[d * 128 + (((s ^ (d & 15))) << 3)] =
            *(const uint4*)(ctxTg + (size_t)bh * 4096 + d * 128 + s * 8);
    }
    if (t < 128) ksumS[t] = ksumg[bh * 128 + t];
    const size_t qeb = ((size_t)bh * 4096 + chunk * 128) * 32;
#pragma unroll
    for (int i = 0; i < 2; ++i) {
        const int u = i * 256 + t;
        ((uint4*)qS)[u] = ((const uint4*)(qg + qeb))[u];
    }
    {
        const int tok = t >> 1, s = 14 + (t & 1);
        *(uint4*)&pS[tok * 128 + (((s ^ (tok & 15))) << 3)] = uint4{0, 0, 0, 0};
    }
    __syncthreads();
    if (t < 128) {
        float s = 0.f;
#pragma unroll
        for (int dq = 0; dq < 4; ++dq) {
            union { uint4 v; u16 ss[8]; } uu;
            uu.v = ((const uint4*)qS)[t * 4 + dq];
#pragma unroll
            for (int j = 0; j < 8; ++j) { const float f = b2f(uu.ss[j]); s = fmaf(f, f, s); }
        }
        diagS[t] = 0.5f * DN2 * s;
    }
    __syncthreads();
    f32x4 dd[7][2];
#pragma unroll
    for (int mb = 0; mb < 7; ++mb)
#pragma unroll
        for (int tb = 0; tb < 2; ++tb) dd[mb][tb] = f32x4{0.f, 0.f, 0.f, 0.f};
    bf16x8 qf[2];
#pragma unroll
    for (int tb = 0; tb < 2; ++tb)
        qf[tb] = *(const bf16x8*)&qS[(w * 32 + tb * 16 + lr) * 32 + lg * 8];
#pragma unroll
    for (int mb = 0; mb < 7; ++mb) {
        const bf16x8 pf = *(const bf16x8*)&projS[(mb * 16 + lr) * 32 + lg * 8];
#pragma unroll
        for (int tb = 0; tb < 2; ++tb)
            dd[mb][tb] = __builtin_amdgcn_mfma_f32_16x16x32_bf16(pf, qf[tb], dd[mb][tb], 0, 0, 0);
    }
    float mx[2], den[2];
#pragma unroll
    for (int tb = 0; tb < 2; ++tb) {
        float v = -INFINITY;
#pragma unroll
        for (int mb = 0; mb < 7; ++mb)
#pragma unroll
            for (int rr = 0; rr < 4; ++rr) {
                if (mb == 6 && (4 * lg + rr) >= 14) continue;
                v = fmaxf(v, dd[mb][tb][rr]);
            }
        v = fmaxf(v, __shfl_xor(v, 16, 64));
        v = fmaxf(v, __shfl_xor(v, 32, 64));
        mx[tb] = v;
        den[tb] = 0.f;
    }
    const float dg0 = diagS[w * 32 + lr], dg1 = diagS[w * 32 + 16 + lr];
#pragma unroll
    for (int mb = 0; mb < 7; ++mb)
#pragma unroll
        for (int tb = 0; tb < 2; ++tb)
#pragma unroll
            for (int rr = 0; rr < 4; ++rr) {
                const int m = mb * 16 + 4 * lg + rr;
                const int tok = w * 32 + tb * 16 + lr;
                const float pv = RATIO * (__expf(dd[mb][tb][rr] - (tb ? dg1 : dg0) - mx[tb]) + KEPS);
                den[tb] += pv * ksumS[m];
                pS[tok * 128 + ((((m >> 3) ^ (tok & 15))) << 3) + (m & 7)] = f2b(pv);
            }
#pragma unroll
    for (int tb = 0; tb < 2; ++tb) {
        den[tb] += __shfl_xor(den[tb], 16, 64);
        den[tb] += __shfl_xor(den[tb], 32, 64);
        if (lg == 0) dinvS[w * 32 + tb * 16 + lr] = 1.f / den[tb];
    }
    __syncthreads();
    f32x4 o[2][2];
#pragma unroll
    for (int i = 0; i < 2; ++i)
#pragma unroll
        for (int j = 0; j < 2; ++j) o[i][j] = f32x4{0.f, 0.f, 0.f, 0.f};
#pragma unroll
    for (int ks = 0; ks < 4; ++ks) {
        bf16x8 aF[2], bF[2];
#pragma unroll
        for (int tb = 0; tb < 2; ++tb) {
            const int tok = w * 32 + tb * 16 + lr;
            aF[tb] = *(const bf16x8*)&pS[tok * 128 + (((ks * 4 + lg) ^ lr) << 3)];
        }
#pragma unroll
        for (int nb = 0; nb < 2; ++nb) {
            const int d = nb * 16 + lr;
            bF[nb] = *(const bf16x8*)&ctxTS[d * 128 + (((ks * 4 + lg) ^ lr) << 3)];
        }
#pragma unroll
        for (int tb = 0; tb < 2; ++tb)
#pragma unroll
            for (int nb = 0; nb < 2; ++nb)
                o[tb][nb] = __builtin_amdgcn_mfma_f32_16x16x32_bf16(aF[tb], bF[nb], o[tb][nb], 0, 0, 0);
    }
    u16* outS = qS;
#pragma unroll
    for (int tb = 0; tb < 2; ++tb)
#pragma unroll
        for (int nb = 0; nb < 2; ++nb)
#pragma unroll
            for (int rr = 0; rr < 4; ++rr) {
                const int tokl = w * 32 + tb * 16 + 4 * lg + rr;
                outS[tokl * 32 + nb * 16 + lr] = f2b(o[tb][nb][rr] * dinvS[tokl]);
            }
    __syncthreads();
#pragma unroll
    for (int i = 0; i < 2; ++i) {
        const int u = i * 256 + t;
        ((uint4*)(ag + qeb))[u] = ((const uint4*)outS)[u];
    }
}

// ---------------- mean-pool partials (h bf16) ----------------
__global__ __launch_bounds__(256) void pool_k(const u16* __restrict__ h,
                                              float* __restrict__ pp)
{
    const int b = blockIdx.x, ch = blockIdx.y, d = threadIdx.x;
    const u16* p = h + ((size_t)b * 4096 + ch * 256) * 256 + d;
    float s = 0.f;
    for (int n = 0; n < 256; ++n) s += b2f(p[(size_t)n * 256]);
    pp[(b * 16 + ch) * 256 + d] = s;
}

// ---------------- classifier head (parallel, 3 stages) ----------------
__global__ __launch_bounds__(256) void cls_a(const float* __restrict__ pp,
                                             const float* __restrict__ g,
                                             const float* __restrict__ bb,
                                             float* __restrict__ zA)
{
    const int b = blockIdx.x, t = threadIdx.x, w = t >> 6, lane = t & 63;
    __shared__ float red1[4], red2[4];
    float s = 0.f;
#pragma unroll
    for (int c = 0; c < 16; ++c) s += pp[(b * 16 + c) * 256 + t];
    const float p = s * (1.f / 4096.f);
    const float s1 = wred_sum(p);
    const float s2 = wred_sum(p * p);
    if (lane == 0) { red1[w] = s1; red2[w] = s2; }
    __syncthreads();
    const float S1 = red1[0] + red1[1] + red1[2] + red1[3];
    const float S2 = red2[0] + red2[1] + red2[2] + red2[3];
    const float mu = S1 * (1.f / 256.f);
    const float var = S2 * (1.f / 256.f) - mu * mu;
    const float rr = rsqrtf(var + 1e-5f);
    zA[b * 256 + t] = fmaxf((p - mu) * rr * g[t] + bb[t], 0.f);
}

__global__ __launch_bounds__(256) void cls_b(const float* __restrict__ zA,
                                             const float* __restrict__ wc1T,
                                             const float* __restrict__ bc1,
                                             float* __restrict__ zB)
{
    const int b = blockIdx.x, t = threadIdx.x;
    __shared__ float zS[256];
    zS[t] = zA[b * 256 + t];
    __syncthreads();
    float s = bc1[t];
    const float* wr = wc1T + (size_t)t * 256;
#pragma unroll
    for (int i = 0; i < 64; ++i) {
        const float4 v = ((const float4*)wr)[i];
        s = fmaf(zS[i * 4 + 0], v.x, s);
        s = fmaf(zS[i * 4 + 1], v.y, s);
        s = fmaf(zS[i * 4 + 2], v.z, s);
        s = fmaf(zS[i * 4 + 3], v.w, s);
    }
    zB[b * 256 + t] = fmaxf(s, 0.f);
}

__global__ __launch_bounds__(256) void cls_c(const float* __restrict__ zB,
                                             const float* __restrict__ wc2,
                                             const float* __restrict__ bc2,
                                             float* __restrict__ out)
{
    const int b = blockIdx.x, t = threadIdx.x, w = t >> 6, lane = t & 63;
    __shared__ float red[4][10];
    const float v = zB[b * 256 + t];
    float a[10];
#pragma unroll
    for (int c = 0; c < 10; ++c) a[c] = v * wc2[t * 10 + c];
#pragma unroll
    for (int c = 0; c < 10; ++c) {
        const float s = wred_sum(a[c]);
        if (lane == 0) red[w][c] = s;
    }
    __syncthreads();
    if (t < 10) out[b * 10 + t] = bc2[t] + red[0][t] + red[1][t] + red[2][t] + red[3][t];
}

// ---------------- host ----------------
extern "C" void kernel_launch(void* const* d_in, const int* in_sizes, int n_in,
                              void* d_out, int out_size, void* d_ws, size_t ws_size,
                              hipStream_t stream)
{
    const float* x    = (const float*)d_in[0];
    const float* w_in = (const float*)d_in[2];
    const float* b_in = (const float*)d_in[3];
    const float* ln1g = (const float*)d_in[4];
    const float* ln1b = (const float*)d_in[5];
    const float* wq   = (const float*)d_in[6];
    const float* wk   = (const float*)d_in[7];
    const float* wv   = (const float*)d_in[8];
    const float* wo   = (const float*)d_in[9];
    const float* bo   = (const float*)d_in[10];
    const float* proj = (const float*)d_in[11];
    const float* ln2g = (const float*)d_in[12];
    const float* ln2b = (const float*)d_in[13];
    const float* w1   = (const float*)d_in[14];
    const float* b1   = (const float*)d_in[15];
    const float* w2   = (const float*)d_in[16];
    const float* b2   = (const float*)d_in[17];
    const float* clsg = (const float*)d_in[18];
    const float* clsb = (const float*)d_in[19];
    const float* wc1  = (const float*)d_in[20];
    const float* bc1  = (const float*)d_in[21];
    const float* wc2  = (const float*)d_in[22];
    const float* bc2  = (const float*)d_in[23];

    char* wsb = (char*)d_ws;
    const size_t MB = 1024 * 1024;
    u16* h     = (u16*)(wsb);                      // 8 MB (bf16 residual stream)
    u16* y     = (u16*)(wsb + 16 * MB);            // 8 MB
    u16* qb    = (u16*)(wsb + 24 * MB);            // 8 MB (head-major)
    u16* kb    = (u16*)(wsb + 32 * MB);            // 8 MB (head-major)
    u16* vb    = (u16*)(wsb + 40 * MB);            // 8 MB (head-major)
    u16* ab    = (u16*)(wsb + 48 * MB);            // 8 MB (head-major)
    u16* xb    = (u16*)(wsb + 56 * MB);            // 4 MB
    u16* wtb   = (u16*)(wsb + 60 * MB);
    u16* w_inT = wtb;                              // 32768
    u16* wqT   = w_inT + 32768;                    // wq/wk/wv consecutive (QKV z-fusion)
    u16* wkT   = wqT + 393216;
    u16* wvT   = wkT + 393216;
    u16* woT   = wvT + 393216;
    u16* w1T   = woT + 393216;                     // 1572864
    u16* w2T   = w1T + 1572864;                    // 1572864
    char* p2   = (char*)(w2T + 1572864);
    float* ctxp  = (float*)p2;                     // 256*112*33 f32
    float* Mcp   = ctxp + 256 * 112 * 33;          // 256
    u16*   ctxTg = (u16*)(Mcp + 256);              // 32*4096
    float* ksumg = (float*)(ctxTg + 32 * 4096);    // 32*128
    float* pp    = ksumg + 32 * 128;               // 16384
    float* vsump = pp + 16384;                     // 256*32
    float* zA    = vsump + 8192;                   // 1024
    float* zB    = zA + 1024;                      // 1024
    float* wc1T  = zB + 1024;                      // 65536 (f32 transposed wc1)

    // weight prep
    trk<<<dim3(8, 4, 1), 256, 0, stream>>>(w_in, w_inT, 128, 256);
    trk<<<dim3(8, 8, 6), 256, 0, stream>>>(wq, wqT, 256, 256);
    trk<<<dim3(8, 8, 6), 256, 0, stream>>>(wk, wkT, 256, 256);
    trk<<<dim3(8, 8, 6), 256, 0, stream>>>(wv, wvT, 256, 256);
    trk<<<dim3(8, 8, 6), 256, 0, stream>>>(wo, woT, 256, 256);
    trk<<<dim3(32, 8, 6), 256, 0, stream>>>(w1, w1T, 256, 1024);
    trk<<<dim3(8, 32, 6), 256, 0, stream>>>(w2, w2T, 1024, 256);
    trkf<<<dim3(8, 8, 1), 256, 0, stream>>>(wc1, wc1T, 256, 256);
    xcast<<<2048, 256, 0, stream>>>(x, xb);

    // input projection + LN1(0) -> y   (K=128, row path)
    gemm3<3, 256, false, false, false, false, 2><<<dim3(1, 256), 512, 0, stream>>>(
        xb, w_inT, b_in, nullptr, 256, h, ln1g, ln1b, y, 128, 128, 1);
    for (int i = 0; i < 6; ++i) {
        const float* proj_i = proj + (size_t)i * 3520;
        // fused QKV (chunk path, NC=4, DEPTH=2, head-major C)
        gemm3<0, 256, true, false, true, true, 2><<<dim3(1, 256, 3), 512, 0, stream>>>(
            y, wqT + (size_t)i * 65536, nullptr, qb, 256,
            nullptr, nullptr, nullptr, nullptr, 256, 256, 1);
        kctx2<<<256, 256, 0, stream>>>(kb, vb, proj_i, ctxp, Mcp, vsump);
        kred2<<<32, 256, 0, stream>>>(ctxp, Mcp, vsump, ctxTg, ksumg);
        qattn2<<<1024, 256, 0, stream>>>(qb, proj_i, ctxTg, ksumg, ab);
        // wo (chunk path, NC=4, DEPTH=3)
        gemm3<2, 256, false, true, false, true, 3><<<dim3(1, 256), 512, 0, stream>>>(
            ab, woT + (size_t)i * 65536, bo + i * 256, nullptr, 256, h,
            ln2g + i * 256, ln2b + i * 256, y, 256, 0, 1);
        // fused FF1+FF2: mid stays in LDS
        if (i < 5)
            ffuse<2><<<256, 512, 0, stream>>>(
                y, w1T + (size_t)i * 262144, b1 + i * 1024,
                w2T + (size_t)i * 262144, b2 + i * 256,
                h, ln1g + (i + 1) * 256, ln1b + (i + 1) * 256, y);
        else
            ffuse<4><<<256, 512, 0, stream>>>(
                y, w1T + (size_t)i * 262144, b1 + i * 1024,
                w2T + (size_t)i * 262144, b2 + i * 256,
                h, nullptr, nullptr, y);
    }
    pool_k<<<dim3(4, 16), 256, 0, stream>>>(h, pp);
    cls_a<<<4, 256, 0, stream>>>(pp, clsg, clsb, zA);
    cls_b<<<4, 256, 0, stream>>>(zA, wc1T, bc1, zB);
    cls_c<<<4, 256, 0, stream>>>(zB, wc2, bc2, (float*)d_out);
}

// Round 16
// 779.312 us; speedup vs baseline: 1.0612x; 1.0612x over previous
//
#include <hip/hip_runtime.h>
#include <cstdint>
#include <cstddef>

typedef __attribute__((ext_vector_type(8))) short bf16x8;
typedef __attribute__((ext_vector_type(4))) float f32x4;
typedef unsigned short u16;
typedef unsigned int u32;

static constexpr float DN    = 0.42044820762685725f;   // 32^-0.25
static constexpr float DN2   = 0.17677669529663687f;   // 32^-0.5
static constexpr float RATIO = 0.09534625892455924f;   // 110^-0.5
static constexpr float KEPS  = 1e-4f;

__device__ __forceinline__ float b2f(u16 u) {
    union { float f; u32 i; } x; x.i = ((u32)u) << 16; return x.f;
}
__device__ __forceinline__ u16 f2b(float f) {
    union { float f; u32 i; } x; x.f = f;
    u32 r = (x.i + 0x7FFFu + ((x.i >> 16) & 1u)) >> 16;
    return (u16)r;
}
__device__ __forceinline__ float wred_sum(float v) {
#pragma unroll
    for (int o = 32; o > 0; o >>= 1) v += __shfl_xor(v, o, 64);
    return v;
}
__device__ __forceinline__ float gelu_f(float v) {
    return 0.5f * v * (1.f + erff(v * 0.7071067811865475f));
}
// async global->LDS, 16B per lane. LDS dest = wave-uniform base + lane*16.
__device__ __forceinline__ void gload16(const u16* g, u16* l) {
    __builtin_amdgcn_global_load_lds(
        (const __attribute__((address_space(1))) u32*)(const u32*)g,
        (__attribute__((address_space(3))) u32*)(u32*)l, 16, 0, 0);
}

// ---------------- weight transpose+cast: src f32 [K][N] -> dst bf16 [N][K] ----------------
__global__ __launch_bounds__(256) void trk(const float* __restrict__ src, u16* __restrict__ dst,
                                           int K, int N)
{
    const size_t bo = (size_t)blockIdx.z * K * N;
    src += bo; dst += bo;
    __shared__ float tl[32][33];
    const int t = threadIdx.x, tx = t & 31, ty = t >> 5;
    const int k0 = blockIdx.y * 32, n0 = blockIdx.x * 32;
#pragma unroll
    for (int p = 0; p < 4; ++p)
        tl[ty + p * 8][tx] = src[(size_t)(k0 + ty + p * 8) * N + n0 + tx];
    __syncthreads();
#pragma unroll
    for (int p = 0; p < 4; ++p)
        dst[(size_t)(n0 + ty + p * 8) * K + k0 + tx] = f2b(tl[tx][ty + p * 8]);
}

// ---------------- f32 transpose (no cast) ----------------
__global__ __launch_bounds__(256) void trkf(const float* __restrict__ src, float* __restrict__ dst,
                                            int K, int N)
{
    __shared__ float tl[32][33];
    const int t = threadIdx.x, tx = t & 31, ty = t >> 5;
    const int k0 = blockIdx.y * 32, n0 = blockIdx.x * 32;
#pragma unroll
    for (int p = 0; p < 4; ++p)
        tl[ty + p * 8][tx] = src[(size_t)(k0 + ty + p * 8) * N + n0 + tx];
    __syncthreads();
#pragma unroll
    for (int p = 0; p < 4; ++p)
        dst[(size_t)(n0 + ty + p * 8) * K + k0 + tx] = tl[tx][ty + p * 8];
}

// ---------------- x cast f32 -> bf16 ----------------
__global__ __launch_bounds__(256) void xcast(const float* __restrict__ x, u16* __restrict__ xb)
{
    const int i = blockIdx.x * 256 + threadIdx.x;
    const float4 v = ((const float4*)x)[i];
    uint2 r;
    r.x = (u32)f2b(v.x) | ((u32)f2b(v.y) << 16);
    r.y = (u32)f2b(v.z) | ((u32)f2b(v.w) << 16);
    ((uint2*)xb)[i] = r;
}

// ---------------- standalone LayerNorm: h(bf16) -> y(bf16) ----------------
__global__ __launch_bounds__(256) void lnk(const u16* __restrict__ h,
                                           const float* __restrict__ g,
                                           const float* __restrict__ bb,
                                           u16* __restrict__ y)
{
    const int row = blockIdx.x * 4 + (threadIdx.x >> 6);
    const int lane = threadIdx.x & 63;
    const uint2 v = *(const uint2*)(h + (size_t)row * 256 + lane * 4);
    float f[4];
    f[0] = b2f((u16)(v.x & 0xFFFF)); f[1] = b2f((u16)(v.x >> 16));
    f[2] = b2f((u16)(v.y & 0xFFFF)); f[3] = b2f((u16)(v.y >> 16));
    float s = f[0] + f[1] + f[2] + f[3];
    float ss = fmaf(f[0], f[0], fmaf(f[1], f[1], fmaf(f[2], f[2], f[3] * f[3])));
    s = wred_sum(s); ss = wred_sum(ss);
    const float mu = s * (1.f / 256.f);
    const float var = ss * (1.f / 256.f) - mu * mu;
    const float rr = rsqrtf(var + 1e-5f);
    const float4 gv = *(const float4*)(g + lane * 4);
    const float4 bv = *(const float4*)(bb + lane * 4);
    uint2 o;
    o.x = (u32)f2b((f[0] - mu) * rr * gv.x + bv.x) | ((u32)f2b((f[1] - mu) * rr * gv.y + bv.y) << 16);
    o.y = (u32)f2b((f[2] - mu) * rr * gv.z + bv.z) | ((u32)f2b((f[3] - mu) * rr * gv.w + bv.w) << 16);
    *(uint2*)(y + (size_t)row * 256 + lane * 4) = o;
}

// ---------------- weight-stationary MFMA GEMM ----------------
// CHUNK=false: row path (B panel resident, A streamed in 64-row tiles), NP=256.
// CHUNK=true: KC=64 chunk pipeline, DEPTH=2 buffers, counted vmcnt.
//   NP=256: full-width (QKV CMODE0/CHEAD, FF1 CMODE1).  BUF=40960, 81920 LDS.
//   NP=128: N-split half panels, CMODE4 only (h += out+bias). BUF=24576, 49152 LDS.
// CMODE: 0 = bf16 out(+bias), 1 = +gelu, 2 = bf16 h += out+bias, + LN->y,
//        3 = bf16 h = out+bias, + LN->y, 4 = bf16 h += out+bias
template<int CMODE, int NP, bool QKV, bool AHEAD, bool CHEAD, bool CHUNK, int DEPTH>
__global__ __launch_bounds__(512) void gemm3(
    const u16* __restrict__ A, const u16* __restrict__ Bt,
    const float* __restrict__ bias, u16* __restrict__ Cb, int ldc,
    u16* __restrict__ hres, const float* __restrict__ lng, const float* __restrict__ lnb,
    u16* __restrict__ yout, int K, int lda, int nrt)
{
    constexpr int KC    = 128;                       // row-path K chunk (NP=256 only)
    constexpr int SLOTS = KC / 8;
    constexpr int SSH   = 4;
    constexpr int BB    = NP * KC * 2;
    constexpr int ABYT  = 64 * KC * 2;
    constexpr int NCB   = NP / 128;                  // 1 or 2
    constexpr int CTS   = (NP == 128) ? 136 : 264;
    constexpr int EPI   = (CMODE <= 1) ? (64 * CTS * 2) : (64 * 264 * 2 + 4608);
    constexpr int KCC   = 64;
    constexpr int BBC   = NP * KCC * 2;              // 32768 / 16384
    constexpr int ABYTC = 64 * KCC * 2;              // 8192
    constexpr int BUF   = BBC + ABYTC;               // 40960 / 24576
    constexpr int LDSZ  = CHUNK ? (DEPTH * BUF) : (BB + 2 * ABYT + EPI);
    __shared__ __align__(16) char smem[LDSZ];

    const u16* Btl = Bt;
    u16* Cbl = Cb;
    if (QKV) { Btl += (size_t)blockIdx.z * 393216; Cbl += (size_t)blockIdx.z * 4194304; }
    const int t = threadIdx.x, w = t >> 6, lr = (t & 63) & 15, lg = (t & 63) >> 4;
    const int p = blockIdx.x;

    char* epi = CHUNK ? smem : (smem + BB + 2 * ABYT);

    f32x4 acc[4][NCB];
    auto ZERO = [&]() {
#pragma unroll
        for (int i = 0; i < 4; ++i)
#pragma unroll
            for (int j = 0; j < NCB; ++j) acc[i][j] = f32x4{0.f, 0.f, 0.f, 0.f};
    };

    auto EPILOGUE = [&](int row0) {
        if constexpr (CMODE <= 1) {
            u16* ctile = (u16*)epi;   // [64][CTS]
            float bv[NCB];
#pragma unroll
            for (int cb = 0; cb < NCB; ++cb) {
                const int col = p * NP + w * (NP / 8) + cb * 16 + lr;
                bv[cb] = bias ? bias[col] : 0.f;
            }
#pragma unroll
            for (int rbk = 0; rbk < 4; ++rbk)
#pragma unroll
                for (int cb = 0; cb < NCB; ++cb)
#pragma unroll
                    for (int rr = 0; rr < 4; ++rr) {
                        const int rl = rbk * 16 + 4 * lg + rr;
                        float v = acc[rbk][cb][rr] + bv[cb];
                        if (CMODE == 1) v = gelu_f(v);
                        ctile[rl * CTS + w * (NP / 8) + cb * 16 + lr] = f2b(v);
                    }
            __syncthreads();
            if constexpr (CHEAD && NP == 256) {
                const int bq = row0 >> 12, n0 = row0 & 4095;
#pragma unroll
                for (int i = 0; i < 4; ++i) {
                    const int u = i * 512 + t;
                    const int row = u >> 5, seg = u & 31;
                    const int hh = seg >> 2, dblk = seg & 3;
                    *(uint4*)(Cbl + ((size_t)(bq * 8 + hh) * 4096 + n0 + row) * 32 + dblk * 8)
                        = *(const uint4*)&ctile[row * 264 + seg * 8];
                }
            } else {
                constexpr int NIT = (NP == 128) ? 2 : 4;
                constexpr int SEGM = NP / 8 - 1;
                constexpr int RSH = (NP == 128) ? 4 : 5;
#pragma unroll
                for (int i = 0; i < NIT; ++i) {
                    const int u = i * 512 + t;
                    const int row = u >> RSH, seg = u & SEGM;
                    *(uint4*)(Cbl + (size_t)(row0 + row) * ldc + p * NP + seg * 8)
                        = *(const uint4*)&ctile[row * CTS + seg * 8];
                }
            }
        } else if constexpr (NP == 128) {
            // lean N-split epilogue (CMODE == 4): h[:, p*128 : p*128+128] += out + bias
            u16* ctile = (u16*)epi;   // [64][136]
            const int cidx = w * 16 + lr;
            const float bv = bias ? bias[p * 128 + cidx] : 0.f;
#pragma unroll
            for (int i = 0; i < 2; ++i) {
                const int u = i * 512 + t;
                const int row = u >> 4, seg = u & 15;
                *(uint4*)&ctile[row * 136 + seg * 8]
                    = *(const uint4*)(hres + (size_t)(row0 + row) * 256 + p * 128 + seg * 8);
            }
            __syncthreads();
#pragma unroll
            for (int rbk = 0; rbk < 4; ++rbk)
#pragma unroll
                for (int rr = 0; rr < 4; ++rr) {
                    const int rl = rbk * 16 + 4 * lg + rr;
                    const float v = acc[rbk][0][rr] + bv + b2f(ctile[rl * 136 + cidx]);
                    ctile[rl * 136 + cidx] = f2b(v);
                }
            __syncthreads();
#pragma unroll
            for (int i = 0; i < 2; ++i) {
                const int u = i * 512 + t;
                const int row = u >> 4, seg = u & 15;
                *(uint4*)(hres + (size_t)(row0 + row) * 256 + p * 128 + seg * 8)
                    = *(const uint4*)&ctile[row * 136 + seg * 8];
            }
        } else {
            // NP == 256 full epilogue (CMODE 2/3/4)
            u16*   ctile = (u16*)epi;                 // [64][264]
            float* rsum  = (float*)(epi + 33792);
            float* rsum2 = rsum + 512;
            float* rmu   = rsum2 + 512;
            float* rrs   = rmu + 64;
            int cidx[NCB]; float bv[NCB];
#pragma unroll
            for (int cb = 0; cb < NCB; ++cb) {
                cidx[cb] = w * 32 + cb * 16 + lr;
                bv[cb] = bias ? bias[cidx[cb]] : 0.f;
            }
            if constexpr (CMODE == 2 || CMODE == 4) {
#pragma unroll
                for (int i = 0; i < 4; ++i) {
                    const int u = i * 512 + t;
                    const int row = u >> 5, seg = u & 31;
                    *(uint4*)&ctile[row * 264 + seg * 8]
                        = *(const uint4*)(hres + (size_t)(row0 + row) * 256 + seg * 8);
                }
                __syncthreads();
            }
#pragma unroll
            for (int rbk = 0; rbk < 4; ++rbk)
#pragma unroll
                for (int cb = 0; cb < NCB; ++cb)
#pragma unroll
                    for (int rr = 0; rr < 4; ++rr) {
                        const int rl = rbk * 16 + 4 * lg + rr;
                        float v = acc[rbk][cb][rr] + bv[cb];
                        if constexpr (CMODE == 2 || CMODE == 4)
                            v += b2f(ctile[rl * 264 + cidx[cb]]);
                        acc[rbk][cb][rr] = v;
                    }
            __syncthreads();
            if constexpr (CMODE != 4) {
#pragma unroll
                for (int rbk = 0; rbk < 4; ++rbk)
#pragma unroll
                    for (int rr = 0; rr < 4; ++rr) {
                        float s1 = acc[rbk][0][rr] + acc[rbk][NCB - 1][rr];
                        float s2 = fmaf(acc[rbk][0][rr], acc[rbk][0][rr],
                                        acc[rbk][NCB - 1][rr] * acc[rbk][NCB - 1][rr]);
#pragma unroll
                        for (int off = 1; off < 16; off <<= 1) {
                            s1 += __shfl_xor(s1, off, 64);
                            s2 += __shfl_xor(s2, off, 64);
                        }
                        if (lr == 0) {
                            const int rl = rbk * 16 + 4 * lg + rr;
                            rsum[rl * 8 + w] = s1; rsum2[rl * 8 + w] = s2;
                        }
                    }
                __syncthreads();
                if (t < 64) {
                    float s1 = 0.f, s2 = 0.f;
#pragma unroll
                    for (int j = 0; j < 8; ++j) { s1 += rsum[t * 8 + j]; s2 += rsum2[t * 8 + j]; }
                    const float mu = s1 * (1.f / 256.f);
                    const float var = s2 * (1.f / 256.f) - mu * mu;
                    rmu[t] = mu; rrs[t] = rsqrtf(var + 1e-5f);
                }
                __syncthreads();
            }
#pragma unroll
            for (int rbk = 0; rbk < 4; ++rbk)
#pragma unroll
                for (int cb = 0; cb < NCB; ++cb)
#pragma unroll
                    for (int rr = 0; rr < 4; ++rr) {
                        const int rl = rbk * 16 + 4 * lg + rr;
                        ctile[rl * 264 + cidx[cb]] = f2b(acc[rbk][cb][rr]);
                    }
            __syncthreads();
#pragma unroll
            for (int i = 0; i < 4; ++i) {
                const int u = i * 512 + t;
                const int row = u >> 5, seg = u & 31;
                *(uint4*)(hres + (size_t)(row0 + row) * 256 + seg * 8)
                    = *(const uint4*)&ctile[row * 264 + seg * 8];
            }
            if constexpr (CMODE != 4) {
                __syncthreads();
                float gv[NCB], bb2[NCB];
#pragma unroll
                for (int cb = 0; cb < NCB; ++cb) { gv[cb] = lng[cidx[cb]]; bb2[cb] = lnb[cidx[cb]]; }
#pragma unroll
                for (int rbk = 0; rbk < 4; ++rbk)
#pragma unroll
                    for (int cb = 0; cb < NCB; ++cb)
#pragma unroll
                        for (int rr = 0; rr < 4; ++rr) {
                            const int rl = rbk * 16 + 4 * lg + rr;
                            const float yv = (acc[rbk][cb][rr] - rmu[rl]) * rrs[rl] * gv[cb] + bb2[cb];
                            ctile[rl * 264 + cidx[cb]] = f2b(yv);
                        }
                __syncthreads();
#pragma unroll
                for (int i = 0; i < 4; ++i) {
                    const int u = i * 512 + t;
                    const int row = u >> 5, seg = u & 31;
                    *(uint4*)(yout + (size_t)(row0 + row) * 256 + seg * 8)
                        = *(const uint4*)&ctile[row * 264 + seg * 8];
                }
            }
        }
    };

    if constexpr (!CHUNK) {
        u16* Bs  = (u16*)smem;
        u16* Asm = (u16*)(smem + BB);
        auto STAGE_B = [&](int c) {
#pragma unroll
            for (int i = 0; i < BB / 16 / 512; ++i) {
                const int u = i * 512 + t;
                const int col = u >> SSH, slot = u & (SLOTS - 1);
                const int gs = slot ^ (col & 7);
                gload16(Btl + (size_t)(p * NP + col) * K + c * KC + gs * 8, Bs + u * 8);
            }
        };
        auto STAGE_A = [&](int c, int row0, int buf) {
            u16* dst = Asm + buf * (ABYT / 2);
#pragma unroll
            for (int i = 0; i < ABYT / 16 / 512; ++i) {
                const int u = i * 512 + t;
                const int row = u >> SSH, slot = u & (SLOTS - 1);
                const int gs = slot ^ (row & 7);
                gload16(A + (size_t)(row0 + row) * lda + c * KC + gs * 8, dst + u * 8);
            }
        };
        auto KLOOP = [&](const u16* AcC) {
#pragma unroll
            for (int ks = 0; ks < KC / 32; ++ks) {
                bf16x8 af[4], bfv[NCB];
#pragma unroll
                for (int rbk = 0; rbk < 4; ++rbk) {
                    const int row = rbk * 16 + lr;
                    af[rbk] = *(const bf16x8*)&AcC[row * KC + (((ks * 4 + lg) ^ (row & 7)) << 3)];
                }
#pragma unroll
                for (int cb = 0; cb < NCB; ++cb) {
                    const int col = w * (NP / 8) + cb * 16 + lr;
                    bfv[cb] = *(const bf16x8*)&Bs[col * KC + (((ks * 4 + lg) ^ (col & 7)) << 3)];
                }
#pragma unroll
                for (int rbk = 0; rbk < 4; ++rbk)
#pragma unroll
                    for (int cb = 0; cb < NCB; ++cb)
                        acc[rbk][cb] = __builtin_amdgcn_mfma_f32_16x16x32_bf16(af[rbk], bfv[cb], acc[rbk][cb], 0, 0, 0);
            }
        };
        int ab = 0;
        STAGE_B(0);
        STAGE_A(0, blockIdx.y * nrt * 64, 0);
        asm volatile("s_waitcnt vmcnt(0)" ::: "memory");
        __syncthreads();
        for (int rt = 0; rt < nrt; ++rt) {
            const int row0 = (blockIdx.y * nrt + rt) * 64;
            if (rt + 1 < nrt) STAGE_A(0, row0 + 64, ab ^ 1);
            ZERO();
            KLOOP(Asm + ab * (ABYT / 2));
            EPILOGUE(row0);
            asm volatile("s_waitcnt vmcnt(0)" ::: "memory");
            __syncthreads();
            ab ^= 1;
        }
    } else {
        // ---- KC=64 chunk pipeline, DEPTH=2 buffers, counted vmcnt ----
        const int NC = K / KCC;
        const int row0 = blockIdx.y * 64;
        auto STAGE_CH = [&](int c, int b) {
            u16* bsB = (u16*)(smem + b * BUF);
            u16* bsA = (u16*)(smem + b * BUF + BBC);
#pragma unroll
            for (int i = 0; i < BBC / 16 / 512; ++i) {      // 4 (NP256) or 2 (NP128) loads
                const int u = i * 512 + t;
                const int col = u >> 3, slot = u & 7;
                const int gs = slot ^ (col & 7);
                gload16(Btl + (size_t)(p * NP + col) * K + c * KCC + gs * 8, bsB + u * 8);
            }
            {                                               // 1 load/thread (A 8KB)
                const int u = t;
                const int row = u >> 3, slot = u & 7;
                const int gs = slot ^ (row & 7);
                const u16* src;
                if (AHEAD) {
                    const int kg = c * KCC + gs * 8;
                    src = A + ((size_t)((row0 >> 12) * 8 + (kg >> 5)) * 4096 + (row0 & 4095) + row) * 32 + (kg & 31);
                } else {
                    src = A + (size_t)(row0 + row) * lda + c * KCC + gs * 8;
                }
                gload16(src, bsA + u * 8);
            }
        };
        auto KLOOP_C = [&](const u16* BsC, const u16* AcC) {
#pragma unroll
            for (int ks = 0; ks < 2; ++ks) {
                bf16x8 af[4], bfv[NCB];
#pragma unroll
                for (int rbk = 0; rbk < 4; ++rbk) {
                    const int row = rbk * 16 + lr;
                    af[rbk] = *(const bf16x8*)&AcC[row * KCC + (((ks * 4 + lg) ^ (row & 7)) << 3)];
                }
#pragma unroll
                for (int cb = 0; cb < NCB; ++cb) {
                    const int col = w * (NP / 8) + cb * 16 + lr;
                    bfv[cb] = *(const bf16x8*)&BsC[col * KCC + (((ks * 4 + lg) ^ (col & 7)) << 3)];
                }
#pragma unroll
                for (int rbk = 0; rbk < 4; ++rbk)
#pragma unroll
                    for (int cb = 0; cb < NCB; ++cb)
                        acc[rbk][cb] = __builtin_amdgcn_mfma_f32_16x16x32_bf16(af[rbk], bfv[cb], acc[rbk][cb], 0, 0, 0);
            }
        };

        ZERO();
        STAGE_CH(0, 0);
        if (1 < NC) STAGE_CH(1, 1);
        for (int c = 0; c < NC; ++c) {
            const int rem = NC - 1 - c;
            if (rem >= 1) {
                if constexpr (NP == 256) asm volatile("s_waitcnt vmcnt(5)" ::: "memory");
                else                     asm volatile("s_waitcnt vmcnt(3)" ::: "memory");
            } else {
                asm volatile("s_waitcnt vmcnt(0)" ::: "memory");
            }
            __builtin_amdgcn_s_barrier();
            __builtin_amdgcn_sched_barrier(0);
            const int cb_ = c & 1;
            KLOOP_C((const u16*)(smem + cb_ * BUF),
                    (const u16*)(smem + cb_ * BUF + BBC));
            __builtin_amdgcn_sched_barrier(0);
            if (c + 2 < NC) {
                __builtin_amdgcn_s_barrier();
                __builtin_amdgcn_sched_barrier(0);
                STAGE_CH(c + 2, cb_);
            }
        }
        __builtin_amdgcn_s_barrier();
        __builtin_amdgcn_sched_barrier(0);
        EPILOGUE(row0);
    }
}

// ---------------- Performer K-side ----------------
__global__ __launch_bounds__(256) void kctx2(
    const u16* __restrict__ kg, const u16* __restrict__ vg,
    const float* __restrict__ proj, float* __restrict__ ctxp, float* __restrict__ Mcp,
    float* __restrict__ vsump)
{
    __shared__ __align__(16) u16 projS[112 * 32];
    __shared__ __align__(16) u16 kS[128 * 32];
    __shared__ __align__(16) u16 vTS[48 * 128];
    __shared__ __align__(16) u16 eTS[112 * 128];
    __shared__ float diagS[128];
    __shared__ float redS[4];
    const int t = threadIdx.x, w = t >> 6, lane = t & 63, lr = lane & 15, lg = lane >> 4;
    const int bh = blockIdx.x >> 3, chunk = blockIdx.x & 7;

    for (int idx = t; idx < 112 * 32; idx += 256) {
        const int m = idx >> 5, d = idx & 31;
        projS[idx] = (m < 110) ? f2b(proj[m * 32 + d] * DN) : (u16)0;
    }
    for (int idx = t; idx < 16 * 128; idx += 256) {
        const int rr = idx >> 7;
        vTS[(32 + rr) * 128 + (idx & 127)] = (rr == 0) ? f2b(1.0f) : (u16)0;
    }
    for (int idx = t; idx < 16 * 128; idx += 256)
        eTS[112 * 128 + idx] = 0;

    f32x4 E[2][3];
#pragma unroll
    for (int i = 0; i < 2; ++i)
#pragma unroll
        for (int j = 0; j < 3; ++j) E[i][j] = f32x4{0.f, 0.f, 0.f, 0.f};
    float Mrun = -INFINITY;
    float vsAcc = 0.f;

    for (int r = 0; r < 4; ++r) {
        const size_t eb = ((size_t)bh * 4096 + chunk * 512 + r * 128) * 32;
#pragma unroll
        for (int i = 0; i < 2; ++i) {
            const int u = i * 256 + t;
            ((uint4*)kS)[u] = ((const uint4*)(kg + eb))[u];
        }
#pragma unroll
        for (int i = 0; i < 2; ++i) {
            const int u = i * 256 + t;
            const int tok = u >> 2, dblk = u & 3;
            union { uint4 v; u16 s[8]; } uu;
            uu.v = ((const uint4*)(vg + eb))[u];
#pragma unroll
            for (int j = 0; j < 8; ++j) {
                const int d = dblk * 8 + j;
                vTS[d * 128 + ((((tok >> 3) ^ (d & 15))) << 3) + (tok & 7)] = uu.s[j];
            }
        }
        __syncthreads();
        {
            const int d = t >> 3, seg = t & 7;
            union { uint4 v; u16 s[8]; } ua, ub;
            ua.v = *(const uint4*)&vTS[d * 128 + seg * 16];
            ub.v = *(const uint4*)&vTS[d * 128 + seg * 16 + 8];
            float s = 0.f;
#pragma unroll
            for (int j = 0; j < 8; ++j) s += b2f(ua.s[j]) + b2f(ub.s[j]);
            vsAcc += s;
        }
        if (t < 128) {
            float s = 0.f;
#pragma unroll
            for (int dq = 0; dq < 4; ++dq) {
                union { uint4 v; u16 ss[8]; } uu;
                uu.v = ((const uint4*)kS)[t * 4 + dq];
#pragma unroll
                for (int j = 0; j < 8; ++j) { const float f = b2f(uu.ss[j]); s = fmaf(f, f, s); }
            }
            diagS[t] = 0.5f * DN2 * s;
        }
        __syncthreads();
        f32x4 dd[7][2];
#pragma unroll
        for (int mb = 0; mb < 7; ++mb)
#pragma unroll
            for (int tb = 0; tb < 2; ++tb) dd[mb][tb] = f32x4{0.f, 0.f, 0.f, 0.f};
        bf16x8 kf[2];
#pragma unroll
        for (int tb = 0; tb < 2; ++tb)
            kf[tb] = *(const bf16x8*)&kS[(w * 32 + tb * 16 + lr) * 32 + lg * 8];
#pragma unroll
        for (int mb = 0; mb < 7; ++mb) {
            const bf16x8 pf = *(const bf16x8*)&projS[(mb * 16 + lr) * 32 + lg * 8];
#pragma unroll
            for (int tb = 0; tb < 2; ++tb)
                dd[mb][tb] = __builtin_amdgcn_mfma_f32_16x16x32_bf16(pf, kf[tb], dd[mb][tb], 0, 0, 0);
        }
        float mx = -INFINITY;
#pragma unroll
        for (int mb = 0; mb < 7; ++mb)
#pragma unroll
            for (int tb = 0; tb < 2; ++tb)
#pragma unroll
                for (int rr = 0; rr < 4; ++rr) {
                    if (mb == 6 && (4 * lg + rr) >= 14) continue;
                    mx = fmaxf(mx, dd[mb][tb][rr]);
                }
#pragma unroll
        for (int off = 1; off < 64; off <<= 1) mx = fmaxf(mx, __shfl_xor(mx, off, 64));
        if (lane == 0) redS[w] = mx;
        __syncthreads();
        float Mnew = fmaxf(fmaxf(redS[0], redS[1]), fmaxf(redS[2], redS[3]));
        Mnew = fmaxf(Mrun, Mnew);
        const float scl = __expf(Mrun - Mnew);
#pragma unroll
        for (int i = 0; i < 2; ++i)
#pragma unroll
            for (int j = 0; j < 3; ++j)
#pragma unroll
                for (int rr = 0; rr < 4; ++rr) E[i][j][rr] *= scl;
        Mrun = Mnew;
        const float dg0 = diagS[w * 32 + lr], dg1 = diagS[w * 32 + 16 + lr];
#pragma unroll
        for (int mb = 0; mb < 7; ++mb)
#pragma unroll
            for (int tb = 0; tb < 2; ++tb)
#pragma unroll
                for (int rr = 0; rr < 4; ++rr) {
                    const int tok = w * 32 + tb * 16 + lr;
                    const int m = mb * 16 + 4 * lg + rr;
                    const float e = __expf(dd[mb][tb][rr] - (tb ? dg1 : dg0) - Mnew);
                    eTS[m * 128 + ((((tok >> 3) ^ (m & 15))) << 3) + (tok & 7)] = f2b(e);
                }
        __syncthreads();
#pragma unroll
        for (int ks = 0; ks < 4; ++ks) {
            bf16x8 aF[2], bF[3];
#pragma unroll
            for (int mb2 = 0; mb2 < 2; ++mb2) {
                const int m = w * 32 + mb2 * 16 + lr;
                aF[mb2] = *(const bf16x8*)&eTS[m * 128 + (((ks * 4 + lg) ^ lr) << 3)];
            }
#pragma unroll
            for (int nb = 0; nb < 3; ++nb) {
                const int d = nb * 16 + lr;
                bF[nb] = *(const bf16x8*)&vTS[d * 128 + (((ks * 4 + lg) ^ lr) << 3)];
            }
#pragma unroll
            for (int mb2 = 0; mb2 < 2; ++mb2)
#pragma unroll
                for (int nb = 0; nb < 3; ++nb)
                    E[mb2][nb] = __builtin_amdgcn_mfma_f32_16x16x32_bf16(aF[mb2], bF[nb], E[mb2][nb], 0, 0, 0);
        }
        __syncthreads();
    }
    const size_t ob = (size_t)blockIdx.x * 112 * 33;
#pragma unroll
    for (int mb2 = 0; mb2 < 2; ++mb2)
#pragma unroll
        for (int nb = 0; nb < 3; ++nb)
#pragma unroll
            for (int rr = 0; rr < 4; ++rr) {
                const int m = w * 32 + mb2 * 16 + 4 * lg + rr;
                if (m < 112) {
                    if (nb < 2) ctxp[ob + m * 33 + nb * 16 + lr] = E[mb2][nb][rr];
                    else if (lr == 0) ctxp[ob + m * 33 + 32] = E[mb2][nb][rr];
                }
            }
    if (t == 0) Mcp[blockIdx.x] = Mrun;
    float vs = vsAcc;
#pragma unroll
    for (int o = 4; o > 0; o >>= 1) vs += __shfl_xor(vs, o, 64);
    if ((t & 7) == 0) vsump[blockIdx.x * 32 + (t >> 3)] = vs;
}

// ---------------- reduce chunk partials -> ctxT + ksum ----------------
__global__ __launch_bounds__(256) void kred2(
    const float* __restrict__ ctxp, const float* __restrict__ Mcp,
    const float* __restrict__ vsump,
    u16* __restrict__ ctxTg, float* __restrict__ ksumg)
{
    __shared__ float vsumS[32];
    __shared__ float wS[8];
    const int t = threadIdx.x, bh = blockIdx.x;
    float M = -INFINITY;
#pragma unroll
    for (int c = 0; c < 8; ++c) M = fmaxf(M, Mcp[bh * 8 + c]);
    if (t < 8) wS[t] = __expf(Mcp[bh * 8 + t] - M);
    if (t < 32) {
        float s = 0.f;
#pragma unroll
        for (int c = 0; c < 8; ++c) s += vsump[(bh * 8 + c) * 32 + t];
        vsumS[t] = s;
    }
    __syncthreads();
    for (int idx = t; idx < 4096; idx += 256) {
        const int d = idx >> 7, m = idx & 127;
        float val = 0.f;
        if (m < 110) {
            float s = 0.f;
#pragma unroll
            for (int c = 0; c < 8; ++c)
                s += wS[c] * ctxp[((size_t)(bh * 8 + c) * 112 + m) * 33 + d];
            val = RATIO * (s + KEPS * vsumS[d]);
        }
        ctxTg[(size_t)bh * 4096 + idx] = f2b(val);
    }
    if (t < 128) {
        float val = 0.f;
        if (t < 110) {
            float s = 0.f;
#pragma unroll
            for (int c = 0; c < 8; ++c)
                s += wS[c] * ctxp[((size_t)(bh * 8 + c) * 112 + t) * 33 + 32];
            val = RATIO * (s + KEPS * 4096.0f);
        }
        ksumg[bh * 128 + t] = val;
    }
}

// ---------------- Performer Q-side ----------------
__global__ __launch_bounds__(256) void qattn2(
    const u16* __restrict__ qg, const float* __restrict__ proj,
    const u16* __restrict__ ctxTg, const float* __restrict__ ksumg, u16* __restrict__ ag)
{
    __shared__ __align__(16) u16 projS[112 * 32];
    __shared__ __align__(16) u16 qS[128 * 32];
    __shared__ __align__(16) u16 ctxTS[32 * 128];
    __shared__ __align__(16) u16 pS[128 * 128];
    __shared__ float ksumS[128], diagS[128], dinvS[128];
    const int t = threadIdx.x, w = t >> 6, lr = (t & 63) & 15, lg = (t & 63) >> 4;
    const int bh = blockIdx.x >> 5, chunk = blockIdx.x & 31;

    for (int idx = t; idx < 112 * 32; idx += 256) {
        const int m = idx >> 5, d = idx & 31;
        projS[idx] = (m < 110) ? f2b(proj[m * 32 + d] * DN) : (u16)0;
    }
#pragma unroll
    for (int i = 0; i < 2; ++i) {
        const int u = i * 256 + t;
        const int d = u >> 4, s = u & 15;
        *(uint4*)&ctxTS[d * 128 + (((s ^ (d & 15))) << 3)] =
            *(const uint4*)(ctxTg + (size_t)bh * 4096 + d * 128 + s * 8);
    }
    if (t < 128) ksumS[t] = ksumg[bh * 128 + t];
    const size_t qeb = ((size_t)bh * 4096 + chunk * 128) * 32;
#pragma unroll
    for (int i = 0; i < 2; ++i) {
        const int u = i * 256 + t;
        ((uint4*)qS)[u] = ((const uint4*)(qg + qeb))[u];
    }
    {
        const int tok = t >> 1, s = 14 + (t & 1);
        *(uint4*)&pS[tok * 128 + (((s ^ (tok & 15))) << 3)] = uint4{0, 0, 0, 0};
    }
    __syncthreads();
    if (t < 128) {
        float s = 0.f;
#pragma unroll
        for (int dq = 0; dq < 4; ++dq) {
            union { uint4 v; u16 ss[8]; } uu;
            uu.v = ((const uint4*)qS)[t * 4 + dq];
#pragma unroll
            for (int j = 0; j < 8; ++j) { const float f = b2f(uu.ss[j]); s = fmaf(f, f, s); }
        }
        diagS[t] = 0.5f * DN2 * s;
    }
    __syncthreads();
    f32x4 dd[7][2];
#pragma unroll
    for (int mb = 0; mb < 7; ++mb)
#pragma unroll
        for (int tb = 0; tb < 2; ++tb) dd[mb][tb] = f32x4{0.f, 0.f, 0.f, 0.f};
    bf16x8 qf[2];
#pragma unroll
    for (int tb = 0; tb < 2; ++tb)
        qf[tb] = *(const bf16x8*)&qS[(w * 32 + tb * 16 + lr) * 32 + lg * 8];
#pragma unroll
    for (int mb = 0; mb < 7; ++mb) {
        const bf16x8 pf = *(const bf16x8*)&projS[(mb * 16 + lr) * 32 + lg * 8];
#pragma unroll
        for (int tb = 0; tb < 2; ++tb)
            dd[mb][tb] = __builtin_amdgcn_mfma_f32_16x16x32_bf16(pf, qf[tb], dd[mb][tb], 0, 0, 0);
    }
    float mx[2], den[2];
#pragma unroll
    for (int tb = 0; tb < 2; ++tb) {
        float v = -INFINITY;
#pragma unroll
        for (int mb = 0; mb < 7; ++mb)
#pragma unroll
            for (int rr = 0; rr < 4; ++rr) {
                if (mb == 6 && (4 * lg + rr) >= 14) continue;
                v = fmaxf(v, dd[mb][tb][rr]);
            }
        v = fmaxf(v, __shfl_xor(v, 16, 64));
        v = fmaxf(v, __shfl_xor(v, 32, 64));
        mx[tb] = v;
        den[tb] = 0.f;
    }
    const float dg0 = diagS[w * 32 + lr], dg1 = diagS[w * 32 + 16 + lr];
#pragma unroll
    for (int mb = 0; mb < 7; ++mb)
#pragma unroll
        for (int tb = 0; tb < 2; ++tb)
#pragma unroll
            for (int rr = 0; rr < 4; ++rr) {
                const int m = mb * 16 + 4 * lg + rr;
                const int tok = w * 32 + tb * 16 + lr;
                const float pv = RATIO * (__expf(dd[mb][tb][rr] - (tb ? dg1 : dg0) - mx[tb]) + KEPS);
                den[tb] += pv * ksumS[m];
                pS[tok * 128 + ((((m >> 3) ^ (tok & 15))) << 3) + (m & 7)] = f2b(pv);
            }
#pragma unroll
    for (int tb = 0; tb < 2; ++tb) {
        den[tb] += __shfl_xor(den[tb], 16, 64);
        den[tb] += __shfl_xor(den[tb], 32, 64);
        if (lg == 0) dinvS[w * 32 + tb * 16 + lr] = 1.f / den[tb];
    }
    __syncthreads();
    f32x4 o[2][2];
#pragma unroll
    for (int i = 0; i < 2; ++i)
#pragma unroll
        for (int j = 0; j < 2; ++j) o[i][j] = f32x4{0.f, 0.f, 0.f, 0.f};
#pragma unroll
    for (int ks = 0; ks < 4; ++ks) {
        bf16x8 aF[2], bF[2];
#pragma unroll
        for (int tb = 0; tb < 2; ++tb) {
            const int tok = w * 32 + tb * 16 + lr;
            aF[tb] = *(const bf16x8*)&pS[tok * 128 + (((ks * 4 + lg) ^ lr) << 3)];
        }
#pragma unroll
        for (int nb = 0; nb < 2; ++nb) {
            const int d = nb * 16 + lr;
            bF[nb] = *(const bf16x8*)&ctxTS[d * 128 + (((ks * 4 + lg) ^ lr) << 3)];
        }
#pragma unroll
        for (int tb = 0; tb < 2; ++tb)
#pragma unroll
            for (int nb = 0; nb < 2; ++nb)
                o[tb][nb] = __builtin_amdgcn_mfma_f32_16x16x32_bf16(aF[tb], bF[nb], o[tb][nb], 0, 0, 0);
    }
    u16* outS = qS;
#pragma unroll
    for (int tb = 0; tb < 2; ++tb)
#pragma unroll
        for (int nb = 0; nb < 2; ++nb)
#pragma unroll
            for (int rr = 0; rr < 4; ++rr) {
                const int tokl = w * 32 + tb * 16 + 4 * lg + rr;
                outS[tokl * 32 + nb * 16 + lr] = f2b(o[tb][nb][rr] * dinvS[tokl]);
            }
    __syncthreads();
#pragma unroll
    for (int i = 0; i < 2; ++i) {
        const int u = i * 256 + t;
        ((uint4*)(ag + qeb))[u] = ((const uint4*)outS)[u];
    }
}

// ---------------- mean-pool partials (h bf16) ----------------
__global__ __launch_bounds__(256) void pool_k(const u16* __restrict__ h,
                                              float* __restrict__ pp)
{
    const int b = blockIdx.x, ch = blockIdx.y, d = threadIdx.x;
    const u16* p = h + ((size_t)b * 4096 + ch * 256) * 256 + d;
    float s = 0.f;
    for (int n = 0; n < 256; ++n) s += b2f(p[(size_t)n * 256]);
    pp[(b * 16 + ch) * 256 + d] = s;
}

// ---------------- classifier head (parallel, 3 stages) ----------------
__global__ __launch_bounds__(256) void cls_a(const float* __restrict__ pp,
                                             const float* __restrict__ g,
                                             const float* __restrict__ bb,
                                             float* __restrict__ zA)
{
    const int b = blockIdx.x, t = threadIdx.x, w = t >> 6, lane = t & 63;
    __shared__ float red1[4], red2[4];
    float s = 0.f;
#pragma unroll
    for (int c = 0; c < 16; ++c) s += pp[(b * 16 + c) * 256 + t];
    const float p = s * (1.f / 4096.f);
    const float s1 = wred_sum(p);
    const float s2 = wred_sum(p * p);
    if (lane == 0) { red1[w] = s1; red2[w] = s2; }
    __syncthreads();
    const float S1 = red1[0] + red1[1] + red1[2] + red1[3];
    const float S2 = red2[0] + red2[1] + red2[2] + red2[3];
    const float mu = S1 * (1.f / 256.f);
    const float var = S2 * (1.f / 256.f) - mu * mu;
    const float rr = rsqrtf(var + 1e-5f);
    zA[b * 256 + t] = fmaxf((p - mu) * rr * g[t] + bb[t], 0.f);
}

__global__ __launch_bounds__(256) void cls_b(const float* __restrict__ zA,
                                             const float* __restrict__ wc1T,
                                             const float* __restrict__ bc1,
                                             float* __restrict__ zB)
{
    const int b = blockIdx.x, t = threadIdx.x;
    __shared__ float zS[256];
    zS[t] = zA[b * 256 + t];
    __syncthreads();
    float s = bc1[t];
    const float* wr = wc1T + (size_t)t * 256;
#pragma unroll
    for (int i = 0; i < 64; ++i) {
        const float4 v = ((const float4*)wr)[i];
        s = fmaf(zS[i * 4 + 0], v.x, s);
        s = fmaf(zS[i * 4 + 1], v.y, s);
        s = fmaf(zS[i * 4 + 2], v.z, s);
        s = fmaf(zS[i * 4 + 3], v.w, s);
    }
    zB[b * 256 + t] = fmaxf(s, 0.f);
}

__global__ __launch_bounds__(256) void cls_c(const float* __restrict__ zB,
                                             const float* __restrict__ wc2,
                                             const float* __restrict__ bc2,
                                             float* __restrict__ out)
{
    const int b = blockIdx.x, t = threadIdx.x, w = t >> 6, lane = t & 63;
    __shared__ float red[4][10];
    const float v = zB[b * 256 + t];
    float a[10];
#pragma unroll
    for (int c = 0; c < 10; ++c) a[c] = v * wc2[t * 10 + c];
#pragma unroll
    for (int c = 0; c < 10; ++c) {
        const float s = wred_sum(a[c]);
        if (lane == 0) red[w][c] = s;
    }
    __syncthreads();
    if (t < 10) out[b * 10 + t] = bc2[t] + red[0][t] + red[1][t] + red[2][t] + red[3][t];
}

// ---------------- host ----------------
extern "C" void kernel_launch(void* const* d_in, const int* in_sizes, int n_in,
                              void* d_out, int out_size, void* d_ws, size_t ws_size,
                              hipStream_t stream)
{
    const float* x    = (const float*)d_in[0];
    const float* w_in = (const float*)d_in[2];
    const float* b_in = (const float*)d_in[3];
    const float* ln1g = (const float*)d_in[4];
    const float* ln1b = (const float*)d_in[5];
    const float* wq   = (const float*)d_in[6];
    const float* wk   = (const float*)d_in[7];
    const float* wv   = (const float*)d_in[8];
    const float* wo   = (const float*)d_in[9];
    const float* bo   = (const float*)d_in[10];
    const float* proj = (const float*)d_in[11];
    const float* ln2g = (const float*)d_in[12];
    const float* ln2b = (const float*)d_in[13];
    const float* w1   = (const float*)d_in[14];
    const float* b1   = (const float*)d_in[15];
    const float* w2   = (const float*)d_in[16];
    const float* b2   = (const float*)d_in[17];
    const float* clsg = (const float*)d_in[18];
    const float* clsb = (const float*)d_in[19];
    const float* wc1  = (const float*)d_in[20];
    const float* bc1  = (const float*)d_in[21];
    const float* wc2  = (const float*)d_in[22];
    const float* bc2  = (const float*)d_in[23];

    char* wsb = (char*)d_ws;
    const size_t MB = 1024 * 1024;
    u16* h     = (u16*)(wsb);                      // 8 MB (bf16 residual stream)
    u16* y     = (u16*)(wsb + 16 * MB);            // 8 MB
    u16* qb    = (u16*)(wsb + 24 * MB);            // 8 MB (head-major)
    u16* kb    = (u16*)(wsb + 32 * MB);            // 8 MB (head-major)
    u16* vb    = (u16*)(wsb + 40 * MB);            // 8 MB (head-major)
    u16* ab    = (u16*)(wsb + 48 * MB);            // 8 MB (head-major)
    u16* mid   = qb;                               // 32 MB spanning q..a (dead in FF phase)
    u16* xb    = (u16*)(wsb + 56 * MB);            // 4 MB
    u16* wtb   = (u16*)(wsb + 60 * MB);
    u16* w_inT = wtb;                              // 32768
    u16* wqT   = w_inT + 32768;                    // wq/wk/wv consecutive (QKV z-fusion)
    u16* wkT   = wqT + 393216;
    u16* wvT   = wkT + 393216;
    u16* woT   = wvT + 393216;
    u16* w1T   = woT + 393216;                     // 1572864
    u16* w2T   = w1T + 1572864;                    // 1572864
    char* p2   = (char*)(w2T + 1572864);
    float* ctxp  = (float*)p2;                     // 256*112*33 f32
    float* Mcp   = ctxp + 256 * 112 * 33;          // 256
    u16*   ctxTg = (u16*)(Mcp + 256);              // 32*4096
    float* ksumg = (float*)(ctxTg + 32 * 4096);    // 32*128
    float* pp    = ksumg + 32 * 128;               // 16384
    float* vsump = pp + 16384;                     // 256*32
    float* zA    = vsump + 8192;                   // 1024
    float* zB    = zA + 1024;                      // 1024
    float* wc1T  = zB + 1024;                      // 65536 (f32 transposed wc1)

    // weight prep
    trk<<<dim3(8, 4, 1), 256, 0, stream>>>(w_in, w_inT, 128, 256);
    trk<<<dim3(8, 8, 6), 256, 0, stream>>>(wq, wqT, 256, 256);
    trk<<<dim3(8, 8, 6), 256, 0, stream>>>(wk, wkT, 256, 256);
    trk<<<dim3(8, 8, 6), 256, 0, stream>>>(wv, wvT, 256, 256);
    trk<<<dim3(8, 8, 6), 256, 0, stream>>>(wo, woT, 256, 256);
    trk<<<dim3(32, 8, 6), 256, 0, stream>>>(w1, w1T, 256, 1024);
    trk<<<dim3(8, 32, 6), 256, 0, stream>>>(w2, w2T, 1024, 256);
    trkf<<<dim3(8, 8, 1), 256, 0, stream>>>(wc1, wc1T, 256, 256);
    xcast<<<2048, 256, 0, stream>>>(x, xb);

    // input projection + LN1(0) -> y   (K=128, row path NP=256)
    gemm3<3, 256, false, false, false, false, 2><<<dim3(1, 256), 512, 0, stream>>>(
        xb, w_inT, b_in, nullptr, 256, h, ln1g, ln1b, y, 128, 128, 1);
    for (int i = 0; i < 6; ++i) {
        const float* proj_i = proj + (size_t)i * 3520;
        // fused QKV (chunk path NP=256, NC=4, head-major C)
        gemm3<0, 256, true, false, true, true, 2><<<dim3(1, 256, 3), 512, 0, stream>>>(
            y, wqT + (size_t)i * 65536, nullptr, qb, 256,
            nullptr, nullptr, nullptr, nullptr, 256, 256, 1);
        kctx2<<<256, 256, 0, stream>>>(kb, vb, proj_i, ctxp, Mcp, vsump);
        kred2<<<32, 256, 0, stream>>>(ctxp, Mcp, vsump, ctxTg, ksumg);
        qattn2<<<1024, 256, 0, stream>>>(qb, proj_i, ctxTg, ksumg, ab);
        // wo: N-split chunk path NP=128, CMODE4 (h += out+bo); then LN2 -> y
        gemm3<4, 128, false, true, false, true, 2><<<dim3(2, 256), 512, 0, stream>>>(
            ab, woT + (size_t)i * 65536, bo + i * 256, nullptr, 256, h,
            nullptr, nullptr, nullptr, 256, 0, 1);
        lnk<<<4096, 256, 0, stream>>>(h, ln2g + i * 256, ln2b + i * 256, y);
        // FF1: chunk path NP=256, 4 col panels, gelu -> mid
        gemm3<1, 256, false, false, false, true, 2><<<dim3(4, 256), 512, 0, stream>>>(
            y, w1T + (size_t)i * 262144, b1 + i * 1024, mid, 1024,
            nullptr, nullptr, nullptr, nullptr, 256, 256, 1);
        // FF2: N-split chunk path NP=128, CMODE4 (h += out+b2); then LN1(i+1) -> y
        gemm3<4, 128, false, false, false, true, 2><<<dim3(2, 256), 512, 0, stream>>>(
            mid, w2T + (size_t)i * 262144, b2 + i * 256, nullptr, 256, h,
            nullptr, nullptr, nullptr, 1024, 1024, 1);
        if (i < 5)
            lnk<<<4096, 256, 0, stream>>>(h, ln1g + (i + 1) * 256, ln1b + (i + 1) * 256, y);
    }
    pool_k<<<dim3(4, 16), 256, 0, stream>>>(h, pp);
    cls_a<<<4, 256, 0, stream>>>(pp, clsg, clsb, zA);
    cls_b<<<4, 256, 0, stream>>>(zA, wc1T, bc1, zB);
    cls_c<<<4, 256, 0, stream>>>(zB, wc2, bc2, (float*)d_out);
}